// Round 1
// baseline (5227.570 us; speedup 1.0000x reference)
//
#include <hip/hip_runtime.h>

#define NEG_SLOPE 0.2f

__device__ inline void atomicMaxF(float* addr, float v) {
    if (v >= 0.f) atomicMax((int*)addr, __float_as_int(v));
    else          atomicMin((unsigned int*)addr, __float_as_uint(v));
}

__device__ inline void edge_sd(const int* __restrict__ ei, int e, int Eo, int& sv, int& dv) {
    if (e < Eo) { sv = ei[e]; dv = ei[Eo + e]; }
    else        { sv = dv = e - Eo; }
}

// ---------------- fill ----------------
__global__ void fill_k(float* __restrict__ p, float v, int count) {
    int i = blockIdx.x * blockDim.x + threadIdx.x;
    if (i < count) p[i] = v;
}

// ---------------- GEMM: Hout[n, NOUT] = X[n, K] @ W[K, NOUT] ----------------
template<int K, int NOUT, int ROWS>
__global__ __launch_bounds__(256) void gemm_rows(const float* __restrict__ X,
                                                 const float* __restrict__ W,
                                                 float* __restrict__ Hout, int nrows) {
    constexpr int NRG = 256 / NOUT;   // row-groups per block
    constexpr int R   = ROWS / NRG;   // rows per thread
    __shared__ float xs[ROWS * (K + 1)];
    const int row0 = blockIdx.x * ROWS;

    for (int idx = threadIdx.x; idx < ROWS * K; idx += 256) {
        int r = idx / K, c = idx % K;
        int gr = row0 + r;
        xs[r * (K + 1) + c] = (gr < nrows) ? X[(size_t)gr * K + c] : 0.f;
    }
    __syncthreads();

    const int col = threadIdx.x % NOUT;
    const int rg  = threadIdx.x / NOUT;
    float acc[R];
#pragma unroll
    for (int i = 0; i < R; i++) acc[i] = 0.f;

    for (int k = 0; k < K; k++) {
        float wk = W[k * NOUT + col];
#pragma unroll
        for (int i = 0; i < R; i++)
            acc[i] += xs[(rg * R + i) * (K + 1) + k] * wk;
    }
#pragma unroll
    for (int i = 0; i < R; i++) {
        int gr = row0 + rg * R + i;
        if (gr < nrows) Hout[(size_t)gr * NOUT + col] = acc[i];
    }
}

// ---------------- per-node attention scores ----------------
__global__ void attn_scores_k(const float* __restrict__ Hfeat, const float* __restrict__ Asrc,
                              const float* __restrict__ Adst, float* __restrict__ esrc,
                              float* __restrict__ edst, int n, int Hh) {
    int gid = blockIdx.x * blockDim.x + threadIdx.x;
    if (gid >= n * Hh) return;
    int node = gid / Hh, h = gid % Hh;
    const float* hp = Hfeat + (size_t)node * Hh * 32 + h * 32;
    const float* as = Asrc + h * 32;
    const float* ad = Adst + h * 32;
    float s1 = 0.f, s2 = 0.f;
#pragma unroll
    for (int c = 0; c < 32; c++) { float v = hp[c]; s1 += v * as[c]; s2 += v * ad[c]; }
    esrc[gid] = s1;
    edst[gid] = s2;
}

// ---------------- segment max over dst ----------------
__global__ void edge_max_k(const int* __restrict__ ei, const float* __restrict__ esrc,
                           const float* __restrict__ edst, float* __restrict__ m,
                           int Eo, int Eext, int Hh) {
    int gid = blockIdx.x * blockDim.x + threadIdx.x;
    if (gid >= Eext * Hh) return;
    int e = gid / Hh, h = gid % Hh;
    int sv, dv; edge_sd(ei, e, Eo, sv, dv);
    float v = esrc[sv * Hh + h] + edst[dv * Hh + h];
    v = (v >= 0.f) ? v : NEG_SLOPE * v;
    atomicMaxF(&m[dv * Hh + h], v);
}

// ---------------- p = exp(e - m[dst]); s = segment_sum(p) ----------------
__global__ void edge_p_sum_k(const int* __restrict__ ei, const float* __restrict__ esrc,
                             const float* __restrict__ edst, const float* __restrict__ m,
                             float* __restrict__ P, float* __restrict__ S,
                             int Eo, int Eext, int Hh) {
    int gid = blockIdx.x * blockDim.x + threadIdx.x;
    if (gid >= Eext * Hh) return;
    int e = gid / Hh, h = gid % Hh;
    int sv, dv; edge_sd(ei, e, Eo, sv, dv);
    float v = esrc[sv * Hh + h] + edst[dv * Hh + h];
    v = (v >= 0.f) ? v : NEG_SLOPE * v;
    float p = __expf(v - m[dv * Hh + h]);
    P[(size_t)e * Hh + h] = p;
    atomicAdd(&S[dv * Hh + h], p);
}

// ---------------- out[dst] += alpha * h[src] ----------------
__global__ void edge_aggr_k(const int* __restrict__ ei, const float* __restrict__ Hfeat,
                            const float* __restrict__ P, const float* __restrict__ S,
                            float* __restrict__ Out, int Eo, int Eext, int Hh) {
    const int HC4 = Hh * 8;  // (Hh*32)/4 float4 chunks per edge
    int gid = blockIdx.x * blockDim.x + threadIdx.x;
    if (gid >= Eext * HC4) return;
    int e = gid / HC4, q = gid % HC4;
    int h = q >> 3;
    int sv, dv; edge_sd(ei, e, Eo, sv, dv);
    float alpha = P[(size_t)e * Hh + h] / (S[dv * Hh + h] + 1e-16f);
    const float4 hv = *(const float4*)(Hfeat + (size_t)sv * Hh * 32 + q * 4);
    float* op = Out + (size_t)dv * Hh * 32 + q * 4;
    atomicAdd(op + 0, alpha * hv.x);
    atomicAdd(op + 1, alpha * hv.y);
    atomicAdd(op + 2, alpha * hv.z);
    atomicAdd(op + 3, alpha * hv.w);
}

// ---------------- out = relu(out + b) ----------------
__global__ void bias_act_k(float* __restrict__ Out, const float* __restrict__ b, int total, int HC) {
    int gid = blockIdx.x * blockDim.x + threadIdx.x;
    if (gid >= total) return;
    float v = Out[gid] + b[gid % HC];
    Out[gid] = v > 0.f ? v : 0.f;
}

// ---------------- edge predictor ----------------
__global__ void predict_k(const int* __restrict__ ei, const float* __restrict__ H3,
                          const float* __restrict__ Wp, const float* __restrict__ bp,
                          float* __restrict__ out, int Eo) {
    int e = blockIdx.x * blockDim.x + threadIdx.x;
    if (e >= Eo) return;
    int sv = ei[e], dv = ei[Eo + e];
    const float* hs = H3 + (size_t)sv * 32;
    const float* hd = H3 + (size_t)dv * 32;
    float acc = bp[0];
#pragma unroll
    for (int c = 0; c < 32; c++) acc += hs[c] * Wp[c] + hd[c] * Wp[32 + c];
    float sg = 1.f / (1.f + __expf(-acc));
    out[e] = sg * 4.f + 1.f;
}

extern "C" void kernel_launch(void* const* d_in, const int* in_sizes, int n_in,
                              void* d_out, int out_size, void* d_ws, size_t ws_size,
                              hipStream_t stream) {
    const float* x   = (const float*)d_in[0];
    const int*   ei  = (const int*)  d_in[1];
    const float* W1  = (const float*)d_in[2];
    const float* as1 = (const float*)d_in[3];
    const float* ad1 = (const float*)d_in[4];
    const float* b1  = (const float*)d_in[5];
    const float* W2  = (const float*)d_in[6];
    const float* as2 = (const float*)d_in[7];
    const float* ad2 = (const float*)d_in[8];
    const float* b2  = (const float*)d_in[9];
    const float* W3  = (const float*)d_in[10];
    const float* as3 = (const float*)d_in[11];
    const float* ad3 = (const float*)d_in[12];
    const float* b3  = (const float*)d_in[13];
    const float* Wp  = (const float*)d_in[14];
    const float* bp  = (const float*)d_in[15];
    float* outp = (float*)d_out;

    const int n    = in_sizes[0] / 128;   // 50000
    const int Eo   = in_sizes[1] / 2;     // 800000
    const int Eext = Eo + n;              // 850000

    float* ws   = (float*)d_ws;
    float* hA   = ws;                          // n*256
    float* hB   = hA + (size_t)n * 256;        // n*256
    float* esrc = hB + (size_t)n * 256;        // n*8
    float* edst = esrc + (size_t)n * 8;        // n*8
    float* mbuf = edst + (size_t)n * 8;        // n*8
    float* sbuf = mbuf + (size_t)n * 8;        // n*8
    float* pbuf = sbuf + (size_t)n * 8;        // Eext*8

    const int TB = 256;
    auto nb = [](int tot, int tb) { return (tot + tb - 1) / tb; };

    // ---------------- Layer 1: K=128, H=8, HC=256 ----------------
    {
        const int Hh = 8, HC = 256;
        gemm_rows<128, 256, 8><<<nb(n, 8), 256, 0, stream>>>(x, W1, hA, n);
        attn_scores_k<<<nb(n * Hh, TB), TB, 0, stream>>>(hA, as1, ad1, esrc, edst, n, Hh);
        fill_k<<<nb(n * Hh, TB), TB, 0, stream>>>(mbuf, -1e38f, n * Hh);
        fill_k<<<nb(n * Hh, TB), TB, 0, stream>>>(sbuf, 0.f, n * Hh);
        fill_k<<<nb(n * HC, TB), TB, 0, stream>>>(hB, 0.f, n * HC);
        edge_max_k<<<nb(Eext * Hh, TB), TB, 0, stream>>>(ei, esrc, edst, mbuf, Eo, Eext, Hh);
        edge_p_sum_k<<<nb(Eext * Hh, TB), TB, 0, stream>>>(ei, esrc, edst, mbuf, pbuf, sbuf, Eo, Eext, Hh);
        edge_aggr_k<<<nb(Eext * Hh * 8, TB), TB, 0, stream>>>(ei, hA, pbuf, sbuf, hB, Eo, Eext, Hh);
        bias_act_k<<<nb(n * HC, TB), TB, 0, stream>>>(hB, b1, n * HC, HC);
    }
    // ---------------- Layer 2: K=256, H=4, HC=128 ----------------
    {
        const int Hh = 4, HC = 128;
        gemm_rows<256, 128, 8><<<nb(n, 8), 256, 0, stream>>>(hB, W2, hA, n);
        attn_scores_k<<<nb(n * Hh, TB), TB, 0, stream>>>(hA, as2, ad2, esrc, edst, n, Hh);
        fill_k<<<nb(n * Hh, TB), TB, 0, stream>>>(mbuf, -1e38f, n * Hh);
        fill_k<<<nb(n * Hh, TB), TB, 0, stream>>>(sbuf, 0.f, n * Hh);
        fill_k<<<nb(n * HC, TB), TB, 0, stream>>>(hB, 0.f, n * HC);
        edge_max_k<<<nb(Eext * Hh, TB), TB, 0, stream>>>(ei, esrc, edst, mbuf, Eo, Eext, Hh);
        edge_p_sum_k<<<nb(Eext * Hh, TB), TB, 0, stream>>>(ei, esrc, edst, mbuf, pbuf, sbuf, Eo, Eext, Hh);
        edge_aggr_k<<<nb(Eext * Hh * 8, TB), TB, 0, stream>>>(ei, hA, pbuf, sbuf, hB, Eo, Eext, Hh);
        bias_act_k<<<nb(n * HC, TB), TB, 0, stream>>>(hB, b2, n * HC, HC);
    }
    // ---------------- Layer 3: K=128, H=1, HC=32 ----------------
    {
        const int Hh = 1, HC = 32;
        gemm_rows<128, 32, 16><<<nb(n, 16), 256, 0, stream>>>(hB, W3, hA, n);
        attn_scores_k<<<nb(n * Hh, TB), TB, 0, stream>>>(hA, as3, ad3, esrc, edst, n, Hh);
        fill_k<<<nb(n * Hh, TB), TB, 0, stream>>>(mbuf, -1e38f, n * Hh);
        fill_k<<<nb(n * Hh, TB), TB, 0, stream>>>(sbuf, 0.f, n * Hh);
        fill_k<<<nb(n * HC, TB), TB, 0, stream>>>(hB, 0.f, n * HC);
        edge_max_k<<<nb(Eext * Hh, TB), TB, 0, stream>>>(ei, esrc, edst, mbuf, Eo, Eext, Hh);
        edge_p_sum_k<<<nb(Eext * Hh, TB), TB, 0, stream>>>(ei, esrc, edst, mbuf, pbuf, sbuf, Eo, Eext, Hh);
        edge_aggr_k<<<nb(Eext * Hh * 8, TB), TB, 0, stream>>>(ei, hA, pbuf, sbuf, hB, Eo, Eext, Hh);
        bias_act_k<<<nb(n * HC, TB), TB, 0, stream>>>(hB, b3, n * HC, HC);
    }
    // ---------------- predictor ----------------
    predict_k<<<nb(Eo, TB), TB, 0, stream>>>(ei, hB, Wp, bp, outp, Eo);
}

// Round 2
// 1309.770 us; speedup vs baseline: 3.9912x; 3.9912x over previous
//
#include <hip/hip_runtime.h>

#define NEG_SLOPE 0.2f

__device__ inline void edge_sd(const int* __restrict__ ei, int e, int Eo, int& sv, int& dv) {
    if (e < Eo) { sv = ei[e]; dv = ei[Eo + e]; }
    else        { sv = dv = e - Eo; }
}

// ---------------- fills ----------------
__global__ void fill_i(int* __restrict__ p, int v, int count) {
    int i = blockIdx.x * blockDim.x + threadIdx.x;
    if (i < count) p[i] = v;
}

// ---------------- CSR build ----------------
__global__ void hist_k(const int* __restrict__ ei, int* __restrict__ cnt, int Eo, int Eext) {
    int e = blockIdx.x * blockDim.x + threadIdx.x;
    if (e >= Eext) return;
    int dv = (e < Eo) ? ei[Eo + e] : (e - Eo);
    atomicAdd(&cnt[dv], 1);
}

// two-level exclusive scan: scan1 (1024 items/block) -> scan2 (block sums) -> scan3 (add)
__global__ __launch_bounds__(256) void scan1_k(const int* __restrict__ cnt, int* __restrict__ rowptr,
                                               int* __restrict__ bsum, int n) {
    __shared__ int ts[256];
    int tid = threadIdx.x;
    int base = blockIdx.x * 1024 + tid * 4;
    int v0 = (base + 0 < n) ? cnt[base + 0] : 0;
    int v1 = (base + 1 < n) ? cnt[base + 1] : 0;
    int v2 = (base + 2 < n) ? cnt[base + 2] : 0;
    int v3 = (base + 3 < n) ? cnt[base + 3] : 0;
    int e1 = v0, e2 = e1 + v1, e3 = e2 + v2, tot = e3 + v3;
    ts[tid] = tot;
    __syncthreads();
    for (int off = 1; off < 256; off <<= 1) {
        int x = (tid >= off) ? ts[tid - off] : 0;
        __syncthreads();
        ts[tid] += x;
        __syncthreads();
    }
    int excl = ts[tid] - tot;
    if (base + 0 < n) rowptr[base + 0] = excl;
    if (base + 1 < n) rowptr[base + 1] = excl + e1;
    if (base + 2 < n) rowptr[base + 2] = excl + e2;
    if (base + 3 < n) rowptr[base + 3] = excl + e3;
    if (tid == 255) bsum[blockIdx.x] = ts[255];
}

__global__ void scan2_k(int* __restrict__ bsum, int nb) {
    if (threadIdx.x == 0 && blockIdx.x == 0) {
        int run = 0;
        for (int i = 0; i < nb; i++) { int t = bsum[i]; bsum[i] = run; run += t; }
    }
}

__global__ void scan3_k(int* __restrict__ rowptr, int* __restrict__ cursors,
                        const int* __restrict__ bsum, int n) {
    int gid = blockIdx.x * blockDim.x + threadIdx.x;
    if (gid >= n) return;
    int v = rowptr[gid] + bsum[gid >> 10];
    rowptr[gid] = v;
    cursors[gid] = v;
}

__global__ void scatter_k(const int* __restrict__ ei, int* __restrict__ cursors,
                          int* __restrict__ csr, int Eo, int Eext) {
    int e = blockIdx.x * blockDim.x + threadIdx.x;
    if (e >= Eext) return;
    int dv = (e < Eo) ? ei[Eo + e] : (e - Eo);
    int idx = atomicAdd(&cursors[dv], 1);
    csr[idx] = e;
}

// deterministic edge order within each node (insertion sort, deg is small)
__global__ void sort_k(const int* __restrict__ rowptr, const int* __restrict__ cnt,
                       int* __restrict__ csr, int n) {
    int node = blockIdx.x * blockDim.x + threadIdx.x;
    if (node >= n) return;
    int ro = rowptr[node], deg = cnt[node];
    for (int i = 1; i < deg; i++) {
        int key = csr[ro + i];
        int j = i - 1;
        while (j >= 0 && csr[ro + j] > key) { csr[ro + j + 1] = csr[ro + j]; j--; }
        csr[ro + j + 1] = key;
    }
}

// ---------------- GEMM: Hout[n, NOUT] = X[n, K] @ W[K, NOUT] ----------------
template<int K, int NOUT, int ROWS>
__global__ __launch_bounds__(256) void gemm_rows(const float* __restrict__ X,
                                                 const float* __restrict__ W,
                                                 float* __restrict__ Hout, int nrows) {
    constexpr int NRG = 256 / NOUT;
    constexpr int R   = ROWS / NRG;
    __shared__ float xs[ROWS * (K + 1)];
    const int row0 = blockIdx.x * ROWS;

    for (int idx = threadIdx.x; idx < ROWS * K; idx += 256) {
        int r = idx / K, c = idx % K;
        int gr = row0 + r;
        xs[r * (K + 1) + c] = (gr < nrows) ? X[(size_t)gr * K + c] : 0.f;
    }
    __syncthreads();

    const int col = threadIdx.x % NOUT;
    const int rg  = threadIdx.x / NOUT;
    float acc[R];
#pragma unroll
    for (int i = 0; i < R; i++) acc[i] = 0.f;

    for (int k = 0; k < K; k++) {
        float wk = W[k * NOUT + col];
#pragma unroll
        for (int i = 0; i < R; i++)
            acc[i] += xs[(rg * R + i) * (K + 1) + k] * wk;
    }
#pragma unroll
    for (int i = 0; i < R; i++) {
        int gr = row0 + rg * R + i;
        if (gr < nrows) Hout[(size_t)gr * NOUT + col] = acc[i];
    }
}

// ---------------- per-node attention scores ----------------
__global__ void attn_scores_k(const float* __restrict__ Hfeat, const float* __restrict__ Asrc,
                              const float* __restrict__ Adst, float* __restrict__ esrc,
                              float* __restrict__ edst, int n, int Hh) {
    int gid = blockIdx.x * blockDim.x + threadIdx.x;
    if (gid >= n * Hh) return;
    int node = gid / Hh, h = gid % Hh;
    const float* hp = Hfeat + (size_t)node * Hh * 32 + h * 32;
    const float* as = Asrc + h * 32;
    const float* ad = Adst + h * 32;
    float s1 = 0.f, s2 = 0.f;
#pragma unroll
    for (int c = 0; c < 32; c++) { float v = hp[c]; s1 += v * as[c]; s2 += v * ad[c]; }
    esrc[gid] = s1;
    edst[gid] = s2;
}

// ---------------- per-(node,head) segment max + exp-sum via CSR ----------------
template<int Hh>
__global__ void node_ms_k(const int* __restrict__ ei, const int* __restrict__ rowptr,
                          const int* __restrict__ cnt, const int* __restrict__ csr,
                          const float* __restrict__ esrc, const float* __restrict__ edst,
                          float* __restrict__ mbuf, float* __restrict__ sbuf, int n, int Eo) {
    int gid = blockIdx.x * blockDim.x + threadIdx.x;
    if (gid >= n * Hh) return;
    int node = gid / Hh, h = gid % Hh;
    int ro = rowptr[node], deg = cnt[node];
    float ed = edst[gid - h + h];  // == edst[node*Hh+h] == edst[gid]
    ed = edst[gid];
    float mx = -1e38f;
    for (int j = 0; j < deg; j++) {
        int eid = csr[ro + j];
        int sv = (eid < Eo) ? ei[eid] : node;
        float v = esrc[sv * Hh + h] + ed;
        v = (v >= 0.f) ? v : NEG_SLOPE * v;
        mx = fmaxf(mx, v);
    }
    float sum = 0.f;
    for (int j = 0; j < deg; j++) {
        int eid = csr[ro + j];
        int sv = (eid < Eo) ? ei[eid] : node;
        float v = esrc[sv * Hh + h] + ed;
        v = (v >= 0.f) ? v : NEG_SLOPE * v;
        sum += __expf(v - mx);
    }
    mbuf[gid] = mx;
    sbuf[gid] = sum;
}

// ---------------- alpha per (edge, head), coalesced write ----------------
template<int Hh>
__global__ void alpha_k(const int* __restrict__ ei, const float* __restrict__ esrc,
                        const float* __restrict__ edst, const float* __restrict__ mbuf,
                        const float* __restrict__ sbuf, float* __restrict__ P,
                        int Eo, int Eext) {
    int gid = blockIdx.x * blockDim.x + threadIdx.x;
    if (gid >= Eext * Hh) return;
    int e = gid / Hh, h = gid % Hh;
    int sv, dv; edge_sd(ei, e, Eo, sv, dv);
    float v = esrc[sv * Hh + h] + edst[dv * Hh + h];
    v = (v >= 0.f) ? v : NEG_SLOPE * v;
    P[gid] = __expf(v - mbuf[dv * Hh + h]) / (sbuf[dv * Hh + h] + 1e-16f);
}

// ---------------- gather-aggregate + bias + relu ----------------
template<int HC, int Hh, int NPB>
__global__ __launch_bounds__(256) void aggr_k(const int* __restrict__ ei, const int* __restrict__ rowptr,
                                              const int* __restrict__ cnt, const int* __restrict__ csr,
                                              const float* __restrict__ P, const float* __restrict__ Hfeat,
                                              const float* __restrict__ bias, float* __restrict__ Out,
                                              int n, int Eo) {
    int node = blockIdx.x * NPB + threadIdx.x / HC;
    int t = threadIdx.x % HC;
    if (node >= n) return;
    int h = t >> 5;
    int ro = rowptr[node], deg = cnt[node];
    float acc = 0.f;
    for (int j = 0; j < deg; j++) {
        int eid = csr[ro + j];
        int src = (eid < Eo) ? ei[eid] : node;
        float a = P[eid * Hh + h];
        acc += a * Hfeat[(size_t)src * HC + t];
    }
    float v = acc + bias[t];
    Out[(size_t)node * HC + t] = v > 0.f ? v : 0.f;
}

// ---------------- edge predictor ----------------
__global__ void predict_k(const int* __restrict__ ei, const float* __restrict__ H3,
                          const float* __restrict__ Wp, const float* __restrict__ bp,
                          float* __restrict__ out, int Eo) {
    int e = blockIdx.x * blockDim.x + threadIdx.x;
    if (e >= Eo) return;
    int sv = ei[e], dv = ei[Eo + e];
    const float* hs = H3 + (size_t)sv * 32;
    const float* hd = H3 + (size_t)dv * 32;
    float acc = bp[0];
#pragma unroll
    for (int c = 0; c < 32; c++) acc += hs[c] * Wp[c] + hd[c] * Wp[32 + c];
    float sg = 1.f / (1.f + __expf(-acc));
    out[e] = sg * 4.f + 1.f;
}

extern "C" void kernel_launch(void* const* d_in, const int* in_sizes, int n_in,
                              void* d_out, int out_size, void* d_ws, size_t ws_size,
                              hipStream_t stream) {
    const float* x   = (const float*)d_in[0];
    const int*   ei  = (const int*)  d_in[1];
    const float* W1  = (const float*)d_in[2];
    const float* as1 = (const float*)d_in[3];
    const float* ad1 = (const float*)d_in[4];
    const float* b1  = (const float*)d_in[5];
    const float* W2  = (const float*)d_in[6];
    const float* as2 = (const float*)d_in[7];
    const float* ad2 = (const float*)d_in[8];
    const float* b2  = (const float*)d_in[9];
    const float* W3  = (const float*)d_in[10];
    const float* as3 = (const float*)d_in[11];
    const float* ad3 = (const float*)d_in[12];
    const float* b3  = (const float*)d_in[13];
    const float* Wp  = (const float*)d_in[14];
    const float* bp  = (const float*)d_in[15];
    float* outp = (float*)d_out;

    const int n    = in_sizes[0] / 128;   // 50000
    const int Eo   = in_sizes[1] / 2;     // 800000
    const int Eext = Eo + n;              // 850000

    float* ws   = (float*)d_ws;
    float* hA   = ws;                           // n*256
    float* hB   = hA + (size_t)n * 256;         // n*256
    float* esrc = hB + (size_t)n * 256;         // n*8
    float* edst = esrc + (size_t)n * 8;         // n*8
    float* mbuf = edst + (size_t)n * 8;         // n*8
    float* sbuf = mbuf + (size_t)n * 8;         // n*8
    float* pbuf = sbuf + (size_t)n * 8;         // Eext*8
    int* cnt     = (int*)(pbuf + (size_t)Eext * 8);  // n
    int* rowptr  = cnt + n;                     // n
    int* cursors = rowptr + n;                  // n
    int* csr     = cursors + n;                 // Eext
    int* bsum    = csr + Eext;                  // ~64

    const int TB = 256;
    auto nb = [](int tot, int tb) { return (tot + tb - 1) / tb; };

    // ---------------- CSR build (dst-sorted) ----------------
    fill_i<<<nb(n, TB), TB, 0, stream>>>(cnt, 0, n);
    hist_k<<<nb(Eext, TB), TB, 0, stream>>>(ei, cnt, Eo, Eext);
    int nChunks = (n + 1023) / 1024;
    scan1_k<<<nChunks, 256, 0, stream>>>(cnt, rowptr, bsum, n);
    scan2_k<<<1, 64, 0, stream>>>(bsum, nChunks);
    scan3_k<<<nb(n, TB), TB, 0, stream>>>(rowptr, cursors, bsum, n);
    scatter_k<<<nb(Eext, TB), TB, 0, stream>>>(ei, cursors, csr, Eo, Eext);
    sort_k<<<nb(n, TB), TB, 0, stream>>>(rowptr, cnt, csr, n);

    // ---------------- Layer 1: K=128, H=8, HC=256 ----------------
    {
        const int Hh = 8;
        gemm_rows<128, 256, 8><<<nb(n, 8), 256, 0, stream>>>(x, W1, hA, n);
        attn_scores_k<<<nb(n * Hh, TB), TB, 0, stream>>>(hA, as1, ad1, esrc, edst, n, Hh);
        node_ms_k<Hh><<<nb(n * Hh, TB), TB, 0, stream>>>(ei, rowptr, cnt, csr, esrc, edst, mbuf, sbuf, n, Eo);
        alpha_k<Hh><<<nb(Eext * Hh, TB), TB, 0, stream>>>(ei, esrc, edst, mbuf, sbuf, pbuf, Eo, Eext);
        aggr_k<256, Hh, 1><<<n, 256, 0, stream>>>(ei, rowptr, cnt, csr, pbuf, hA, b1, hB, n, Eo);
    }
    // ---------------- Layer 2: K=256, H=4, HC=128 ----------------
    {
        const int Hh = 4;
        gemm_rows<256, 128, 8><<<nb(n, 8), 256, 0, stream>>>(hB, W2, hA, n);
        attn_scores_k<<<nb(n * Hh, TB), TB, 0, stream>>>(hA, as2, ad2, esrc, edst, n, Hh);
        node_ms_k<Hh><<<nb(n * Hh, TB), TB, 0, stream>>>(ei, rowptr, cnt, csr, esrc, edst, mbuf, sbuf, n, Eo);
        alpha_k<Hh><<<nb(Eext * Hh, TB), TB, 0, stream>>>(ei, esrc, edst, mbuf, sbuf, pbuf, Eo, Eext);
        aggr_k<128, Hh, 2><<<nb(n, 2), 256, 0, stream>>>(ei, rowptr, cnt, csr, pbuf, hA, b2, hB, n, Eo);
    }
    // ---------------- Layer 3: K=128, H=1, HC=32 ----------------
    {
        const int Hh = 1;
        gemm_rows<128, 32, 16><<<nb(n, 16), 256, 0, stream>>>(hB, W3, hA, n);
        attn_scores_k<<<nb(n * Hh, TB), TB, 0, stream>>>(hA, as3, ad3, esrc, edst, n, Hh);
        node_ms_k<Hh><<<nb(n * Hh, TB), TB, 0, stream>>>(ei, rowptr, cnt, csr, esrc, edst, mbuf, sbuf, n, Eo);
        alpha_k<Hh><<<nb(Eext * Hh, TB), TB, 0, stream>>>(ei, esrc, edst, mbuf, sbuf, pbuf, Eo, Eext);
        aggr_k<32, Hh, 8><<<nb(n, 8), 256, 0, stream>>>(ei, rowptr, cnt, csr, pbuf, hA, b3, hB, n, Eo);
    }
    // ---------------- predictor ----------------
    predict_k<<<nb(Eo, TB), TB, 0, stream>>>(ei, hB, Wp, bp, outp, Eo);
}

// Round 3
// 745.708 us; speedup vs baseline: 7.0102x; 1.7564x over previous
//
#include <hip/hip_runtime.h>

#define NEG_SLOPE 0.2f

// ---------------- fills ----------------
__global__ void fill_i(int* __restrict__ p, int v, int count) {
    int i = blockIdx.x * blockDim.x + threadIdx.x;
    if (i < count) p[i] = v;
}

// ---------------- CSR build ----------------
__global__ void hist_k(const int* __restrict__ ei, int* __restrict__ cnt, int Eo, int Eext) {
    int e = blockIdx.x * blockDim.x + threadIdx.x;
    if (e >= Eext) return;
    int dv = (e < Eo) ? ei[Eo + e] : (e - Eo);
    atomicAdd(&cnt[dv], 1);
}

__global__ __launch_bounds__(256) void scan1_k(const int* __restrict__ cnt, int* __restrict__ rowptr,
                                               int* __restrict__ bsum, int n) {
    __shared__ int ts[256];
    int tid = threadIdx.x;
    int base = blockIdx.x * 1024 + tid * 4;
    int v0 = (base + 0 < n) ? cnt[base + 0] : 0;
    int v1 = (base + 1 < n) ? cnt[base + 1] : 0;
    int v2 = (base + 2 < n) ? cnt[base + 2] : 0;
    int v3 = (base + 3 < n) ? cnt[base + 3] : 0;
    int e1 = v0, e2 = e1 + v1, e3 = e2 + v2, tot = e3 + v3;
    ts[tid] = tot;
    __syncthreads();
    for (int off = 1; off < 256; off <<= 1) {
        int x = (tid >= off) ? ts[tid - off] : 0;
        __syncthreads();
        ts[tid] += x;
        __syncthreads();
    }
    int excl = ts[tid] - tot;
    if (base + 0 < n) rowptr[base + 0] = excl;
    if (base + 1 < n) rowptr[base + 1] = excl + e1;
    if (base + 2 < n) rowptr[base + 2] = excl + e2;
    if (base + 3 < n) rowptr[base + 3] = excl + e3;
    if (tid == 255) bsum[blockIdx.x] = ts[255];
}

__global__ void scan2_k(int* __restrict__ bsum, int nb) {
    if (threadIdx.x == 0 && blockIdx.x == 0) {
        int run = 0;
        for (int i = 0; i < nb; i++) { int t = bsum[i]; bsum[i] = run; run += t; }
    }
}

__global__ void scan3_k(int* __restrict__ rowptr, int* __restrict__ cursors,
                        const int* __restrict__ bsum, int n) {
    int gid = blockIdx.x * blockDim.x + threadIdx.x;
    if (gid >= n) return;
    int v = rowptr[gid] + bsum[gid >> 10];
    rowptr[gid] = v;
    cursors[gid] = v;
}

__global__ void scatter_k(const int* __restrict__ ei, int* __restrict__ cursors,
                          int* __restrict__ csr, int Eo, int Eext) {
    int e = blockIdx.x * blockDim.x + threadIdx.x;
    if (e >= Eext) return;
    int dv = (e < Eo) ? ei[Eo + e] : (e - Eo);
    int idx = atomicAdd(&cursors[dv], 1);
    csr[idx] = e;
}

// deterministic edge order within node + precompute src per CSR slot
__global__ void sort_k(const int* __restrict__ rowptr, const int* __restrict__ cnt,
                       int* __restrict__ csr, const int* __restrict__ ei,
                       int* __restrict__ csr_src, int n, int Eo) {
    int node = blockIdx.x * blockDim.x + threadIdx.x;
    if (node >= n) return;
    int ro = rowptr[node], deg = cnt[node];
    for (int i = 1; i < deg; i++) {
        int key = csr[ro + i];
        int j = i - 1;
        while (j >= 0 && csr[ro + j] > key) { csr[ro + j + 1] = csr[ro + j]; j--; }
        csr[ro + j + 1] = key;
    }
    for (int i = 0; i < deg; i++) {
        int eid = csr[ro + i];
        csr_src[ro + i] = (eid < Eo) ? ei[eid] : node;
    }
}

// ---------------- GEMM: Hout[n, NOUT] = X[n, K] @ W[K, NOUT] ----------------
template<int K, int NOUT, int ROWS>
__global__ __launch_bounds__(256) void gemm_rows(const float* __restrict__ X,
                                                 const float* __restrict__ W,
                                                 float* __restrict__ Hout, int nrows) {
    constexpr int NRG = 256 / NOUT;
    constexpr int R   = ROWS / NRG;
    __shared__ float xs[ROWS * (K + 1)];
    const int row0 = blockIdx.x * ROWS;

    for (int idx = threadIdx.x; idx < ROWS * K; idx += 256) {
        int r = idx / K, c = idx % K;
        int gr = row0 + r;
        xs[r * (K + 1) + c] = (gr < nrows) ? X[(size_t)gr * K + c] : 0.f;
    }
    __syncthreads();

    const int col = threadIdx.x % NOUT;
    const int rg  = threadIdx.x / NOUT;
    float acc[R];
#pragma unroll
    for (int i = 0; i < R; i++) acc[i] = 0.f;

    for (int k = 0; k < K; k++) {
        float wk = W[k * NOUT + col];
#pragma unroll
        for (int i = 0; i < R; i++)
            acc[i] += xs[(rg * R + i) * (K + 1) + k] * wk;
    }
#pragma unroll
    for (int i = 0; i < R; i++) {
        int gr = row0 + rg * R + i;
        if (gr < nrows) Hout[(size_t)gr * NOUT + col] = acc[i];
    }
}

// ---------------- per-node attention scores ----------------
__global__ void attn_scores_k(const float* __restrict__ Hfeat, const float* __restrict__ Asrc,
                              const float* __restrict__ Adst, float* __restrict__ esrc,
                              float* __restrict__ edst, int n, int Hh) {
    int gid = blockIdx.x * blockDim.x + threadIdx.x;
    if (gid >= n * Hh) return;
    int node = gid / Hh, h = gid % Hh;
    const float* hp = Hfeat + (size_t)node * Hh * 32 + h * 32;
    const float* as = Asrc + h * 32;
    const float* ad = Adst + h * 32;
    float s1 = 0.f, s2 = 0.f;
#pragma unroll
    for (int c = 0; c < 32; c++) { float v = hp[c]; s1 += v * as[c]; s2 += v * ad[c]; }
    esrc[gid] = s1;
    edst[gid] = s2;
}

// ---------------- per-(node,head): max, exp-sum, and alpha in CSR slot order ----------------
template<int Hh>
__global__ void node_msa_k(const int* __restrict__ rowptr, const int* __restrict__ cnt,
                           const int* __restrict__ csr_src,
                           const float* __restrict__ esrc, const float* __restrict__ edst,
                           float* __restrict__ A, int n) {
    int gid = blockIdx.x * blockDim.x + threadIdx.x;
    if (gid >= n * Hh) return;
    int node = gid / Hh, h = gid % Hh;
    int ro = rowptr[node], deg = cnt[node];
    float ed = edst[gid];
    float mx = -1e38f;
    for (int j = 0; j < deg; j++) {
        int sv = csr_src[ro + j];
        float v = esrc[sv * Hh + h] + ed;
        v = (v >= 0.f) ? v : NEG_SLOPE * v;
        mx = fmaxf(mx, v);
    }
    float sum = 0.f;
    for (int j = 0; j < deg; j++) {
        int sv = csr_src[ro + j];
        float v = esrc[sv * Hh + h] + ed;
        v = (v >= 0.f) ? v : NEG_SLOPE * v;
        float p = __expf(v - mx);
        sum += p;
        A[(size_t)(ro + j) * Hh + h] = p;
    }
    float inv = 1.f / (sum + 1e-16f);
    for (int j = 0; j < deg; j++)
        A[(size_t)(ro + j) * Hh + h] *= inv;
}

// ---------------- gather-aggregate (float4, unroll-4) + bias + relu ----------------
template<int HC, int Hh>
__global__ __launch_bounds__(256) void aggr4_k(const int* __restrict__ rowptr, const int* __restrict__ cnt,
                                               const int* __restrict__ csr_src, const float* __restrict__ A,
                                               const float* __restrict__ Hfeat, const float* __restrict__ bias,
                                               float* __restrict__ Out, int n) {
    constexpr int TPN = HC / 4;       // threads per node
    constexpr int NPB = 256 / TPN;    // nodes per block
    int node = blockIdx.x * NPB + threadIdx.x / TPN;
    if (node >= n) return;
    int t = threadIdx.x % TPN;
    int h = (4 * t) >> 5;
    int ro = rowptr[node], deg = cnt[node];
    float4 acc = make_float4(0.f, 0.f, 0.f, 0.f);
    int j = 0;
    for (; j + 4 <= deg; j += 4) {
        int s0 = csr_src[ro + j + 0], s1 = csr_src[ro + j + 1];
        int s2 = csr_src[ro + j + 2], s3 = csr_src[ro + j + 3];
        float a0 = A[(size_t)(ro + j + 0) * Hh + h];
        float a1 = A[(size_t)(ro + j + 1) * Hh + h];
        float a2 = A[(size_t)(ro + j + 2) * Hh + h];
        float a3 = A[(size_t)(ro + j + 3) * Hh + h];
        float4 v0 = *(const float4*)(Hfeat + (size_t)s0 * HC + 4 * t);
        float4 v1 = *(const float4*)(Hfeat + (size_t)s1 * HC + 4 * t);
        float4 v2 = *(const float4*)(Hfeat + (size_t)s2 * HC + 4 * t);
        float4 v3 = *(const float4*)(Hfeat + (size_t)s3 * HC + 4 * t);
        acc.x += a0 * v0.x + a1 * v1.x + a2 * v2.x + a3 * v3.x;
        acc.y += a0 * v0.y + a1 * v1.y + a2 * v2.y + a3 * v3.y;
        acc.z += a0 * v0.z + a1 * v1.z + a2 * v2.z + a3 * v3.z;
        acc.w += a0 * v0.w + a1 * v1.w + a2 * v2.w + a3 * v3.w;
    }
    for (; j < deg; j++) {
        int s0 = csr_src[ro + j];
        float a0 = A[(size_t)(ro + j) * Hh + h];
        float4 v0 = *(const float4*)(Hfeat + (size_t)s0 * HC + 4 * t);
        acc.x += a0 * v0.x; acc.y += a0 * v0.y; acc.z += a0 * v0.z; acc.w += a0 * v0.w;
    }
    float4 b4 = *(const float4*)(bias + 4 * t);
    acc.x += b4.x; acc.y += b4.y; acc.z += b4.z; acc.w += b4.w;
    acc.x = acc.x > 0.f ? acc.x : 0.f;
    acc.y = acc.y > 0.f ? acc.y : 0.f;
    acc.z = acc.z > 0.f ? acc.z : 0.f;
    acc.w = acc.w > 0.f ? acc.w : 0.f;
    *(float4*)(Out + (size_t)node * HC + 4 * t) = acc;
}

// ---------------- edge predictor (float4) ----------------
__global__ void predict_k(const int* __restrict__ ei, const float* __restrict__ H3,
                          const float* __restrict__ Wp, const float* __restrict__ bp,
                          float* __restrict__ out, int Eo) {
    int e = blockIdx.x * blockDim.x + threadIdx.x;
    if (e >= Eo) return;
    int sv = ei[e], dv = ei[Eo + e];
    const float4* hs = (const float4*)(H3 + (size_t)sv * 32);
    const float4* hd = (const float4*)(H3 + (size_t)dv * 32);
    const float4* w1 = (const float4*)Wp;
    const float4* w2 = (const float4*)(Wp + 32);
    float acc = bp[0];
#pragma unroll
    for (int q = 0; q < 8; q++) {
        float4 a = hs[q], w = w1[q];
        acc += a.x * w.x + a.y * w.y + a.z * w.z + a.w * w.w;
    }
#pragma unroll
    for (int q = 0; q < 8; q++) {
        float4 a = hd[q], w = w2[q];
        acc += a.x * w.x + a.y * w.y + a.z * w.z + a.w * w.w;
    }
    float sg = 1.f / (1.f + __expf(-acc));
    out[e] = sg * 4.f + 1.f;
}

extern "C" void kernel_launch(void* const* d_in, const int* in_sizes, int n_in,
                              void* d_out, int out_size, void* d_ws, size_t ws_size,
                              hipStream_t stream) {
    const float* x   = (const float*)d_in[0];
    const int*   ei  = (const int*)  d_in[1];
    const float* W1  = (const float*)d_in[2];
    const float* as1 = (const float*)d_in[3];
    const float* ad1 = (const float*)d_in[4];
    const float* b1  = (const float*)d_in[5];
    const float* W2  = (const float*)d_in[6];
    const float* as2 = (const float*)d_in[7];
    const float* ad2 = (const float*)d_in[8];
    const float* b2  = (const float*)d_in[9];
    const float* W3  = (const float*)d_in[10];
    const float* as3 = (const float*)d_in[11];
    const float* ad3 = (const float*)d_in[12];
    const float* b3  = (const float*)d_in[13];
    const float* Wp  = (const float*)d_in[14];
    const float* bp  = (const float*)d_in[15];
    float* outp = (float*)d_out;

    const int n    = in_sizes[0] / 128;   // 50000
    const int Eo   = in_sizes[1] / 2;     // 800000
    const int Eext = Eo + n;              // 850000

    float* ws   = (float*)d_ws;
    float* hA   = ws;                           // n*256
    float* hB   = hA + (size_t)n * 256;         // n*256
    float* esrc = hB + (size_t)n * 256;         // n*8
    float* edst = esrc + (size_t)n * 8;         // n*8
    float* abuf = edst + (size_t)n * 8;         // Eext*8 (alpha in CSR slot order)
    int* cnt     = (int*)(abuf + (size_t)Eext * 8);  // n
    int* rowptr  = cnt + n;                     // n
    int* cursors = rowptr + n;                  // n
    int* csr     = cursors + n;                 // Eext
    int* csr_src = csr + Eext;                  // Eext
    int* bsum    = csr_src + Eext;              // ~64

    const int TB = 256;
    auto nb = [](int tot, int tb) { return (tot + tb - 1) / tb; };

    // ---------------- CSR build (dst-sorted) ----------------
    fill_i<<<nb(n, TB), TB, 0, stream>>>(cnt, 0, n);
    hist_k<<<nb(Eext, TB), TB, 0, stream>>>(ei, cnt, Eo, Eext);
    int nChunks = (n + 1023) / 1024;
    scan1_k<<<nChunks, 256, 0, stream>>>(cnt, rowptr, bsum, n);
    scan2_k<<<1, 64, 0, stream>>>(bsum, nChunks);
    scan3_k<<<nb(n, TB), TB, 0, stream>>>(rowptr, cursors, bsum, n);
    scatter_k<<<nb(Eext, TB), TB, 0, stream>>>(ei, cursors, csr, Eo, Eext);
    sort_k<<<nb(n, TB), TB, 0, stream>>>(rowptr, cnt, csr, ei, csr_src, n, Eo);

    // ---------------- Layer 1: K=128, H=8, HC=256 ----------------
    {
        const int Hh = 8;
        gemm_rows<128, 256, 16><<<nb(n, 16), 256, 0, stream>>>(x, W1, hA, n);
        attn_scores_k<<<nb(n * Hh, TB), TB, 0, stream>>>(hA, as1, ad1, esrc, edst, n, Hh);
        node_msa_k<Hh><<<nb(n * Hh, TB), TB, 0, stream>>>(rowptr, cnt, csr_src, esrc, edst, abuf, n);
        aggr4_k<256, Hh><<<nb(n, 4), 256, 0, stream>>>(rowptr, cnt, csr_src, abuf, hA, b1, hB, n);
    }
    // ---------------- Layer 2: K=256, H=4, HC=128 ----------------
    {
        const int Hh = 4;
        gemm_rows<256, 128, 16><<<nb(n, 16), 256, 0, stream>>>(hB, W2, hA, n);
        attn_scores_k<<<nb(n * Hh, TB), TB, 0, stream>>>(hA, as2, ad2, esrc, edst, n, Hh);
        node_msa_k<Hh><<<nb(n * Hh, TB), TB, 0, stream>>>(rowptr, cnt, csr_src, esrc, edst, abuf, n);
        aggr4_k<128, Hh><<<nb(n, 8), 256, 0, stream>>>(rowptr, cnt, csr_src, abuf, hA, b2, hB, n);
    }
    // ---------------- Layer 3: K=128, H=1, HC=32 ----------------
    {
        const int Hh = 1;
        gemm_rows<128, 32, 32><<<nb(n, 32), 256, 0, stream>>>(hB, W3, hA, n);
        attn_scores_k<<<nb(n * Hh, TB), TB, 0, stream>>>(hA, as3, ad3, esrc, edst, n, Hh);
        node_msa_k<Hh><<<nb(n * Hh, TB), TB, 0, stream>>>(rowptr, cnt, csr_src, esrc, edst, abuf, n);
        aggr4_k<32, Hh><<<nb(n, 32), 256, 0, stream>>>(rowptr, cnt, csr_src, abuf, hA, b3, hB, n);
    }
    // ---------------- predictor ----------------
    predict_k<<<nb(Eo, TB), TB, 0, stream>>>(ei, hB, Wp, bp, outp, Eo);
}

// Round 4
// 552.486 us; speedup vs baseline: 9.4619x; 1.3497x over previous
//
#include <hip/hip_runtime.h>

#define NEG_SLOPE 0.2f

__device__ inline unsigned short f2bf(float f) {
    unsigned int u = __float_as_uint(f);
    unsigned int r = (u + 0x7fffu + ((u >> 16) & 1u)) >> 16;
    return (unsigned short)r;
}

// ---------------- fills ----------------
__global__ void fill_i(int* __restrict__ p, int v, int count) {
    int i = blockIdx.x * blockDim.x + threadIdx.x;
    if (i < count) p[i] = v;
}

// ---------------- CSR build ----------------
__global__ void hist_k(const int* __restrict__ ei, int* __restrict__ cnt, int Eo, int Eext) {
    int e = blockIdx.x * blockDim.x + threadIdx.x;
    if (e >= Eext) return;
    int dv = (e < Eo) ? ei[Eo + e] : (e - Eo);
    atomicAdd(&cnt[dv], 1);
}

__global__ __launch_bounds__(256) void scan1_k(const int* __restrict__ cnt, int* __restrict__ rowptr,
                                               int* __restrict__ bsum, int n) {
    __shared__ int ts[256];
    int tid = threadIdx.x;
    int base = blockIdx.x * 1024 + tid * 4;
    int v0 = (base + 0 < n) ? cnt[base + 0] : 0;
    int v1 = (base + 1 < n) ? cnt[base + 1] : 0;
    int v2 = (base + 2 < n) ? cnt[base + 2] : 0;
    int v3 = (base + 3 < n) ? cnt[base + 3] : 0;
    int e1 = v0, e2 = e1 + v1, e3 = e2 + v2, tot = e3 + v3;
    ts[tid] = tot;
    __syncthreads();
    for (int off = 1; off < 256; off <<= 1) {
        int x = (tid >= off) ? ts[tid - off] : 0;
        __syncthreads();
        ts[tid] += x;
        __syncthreads();
    }
    int excl = ts[tid] - tot;
    if (base + 0 < n) rowptr[base + 0] = excl;
    if (base + 1 < n) rowptr[base + 1] = excl + e1;
    if (base + 2 < n) rowptr[base + 2] = excl + e2;
    if (base + 3 < n) rowptr[base + 3] = excl + e3;
    if (tid == 255) bsum[blockIdx.x] = ts[255];
}

__global__ void scan2_k(int* __restrict__ bsum, int nb) {
    if (threadIdx.x == 0 && blockIdx.x == 0) {
        int run = 0;
        for (int i = 0; i < nb; i++) { int t = bsum[i]; bsum[i] = run; run += t; }
    }
}

__global__ void scan3_k(int* __restrict__ rowptr, int* __restrict__ cursors,
                        const int* __restrict__ bsum, int n) {
    int gid = blockIdx.x * blockDim.x + threadIdx.x;
    if (gid >= n) return;
    int v = rowptr[gid] + bsum[gid >> 10];
    rowptr[gid] = v;
    cursors[gid] = v;
}

__global__ void scatter_k(const int* __restrict__ ei, int* __restrict__ cursors,
                          int* __restrict__ csr, int Eo, int Eext) {
    int e = blockIdx.x * blockDim.x + threadIdx.x;
    if (e >= Eext) return;
    int dv = (e < Eo) ? ei[Eo + e] : (e - Eo);
    int idx = atomicAdd(&cursors[dv], 1);
    csr[idx] = e;
}

__global__ void sort_k(const int* __restrict__ rowptr, const int* __restrict__ cnt,
                       int* __restrict__ csr, const int* __restrict__ ei,
                       int* __restrict__ csr_src, int n, int Eo) {
    int node = blockIdx.x * blockDim.x + threadIdx.x;
    if (node >= n) return;
    int ro = rowptr[node], deg = cnt[node];
    for (int i = 1; i < deg; i++) {
        int key = csr[ro + i];
        int j = i - 1;
        while (j >= 0 && csr[ro + j] > key) { csr[ro + j + 1] = csr[ro + j]; j--; }
        csr[ro + j + 1] = key;
    }
    for (int i = 0; i < deg; i++) {
        int eid = csr[ro + i];
        csr_src[ro + i] = (eid < Eo) ? ei[eid] : node;
    }
}

// ---------------- GEMM + fused attention scores + bf16 output ----------------
// Hb[n,NOUT] (bf16) = X[n,K] @ W[K,NOUT]; esrc/edst[n,Hh] = per-head dots with As/Ad.
template<int K, int NOUT, int ROWS, int Hh>
__global__ __launch_bounds__(256) void gemm_fused(const float* __restrict__ X,
                                                  const float* __restrict__ W,
                                                  const float* __restrict__ As,
                                                  const float* __restrict__ Ad,
                                                  unsigned short* __restrict__ Hb,
                                                  float* __restrict__ esrc,
                                                  float* __restrict__ edst, int nrows) {
    constexpr int QUADS = NOUT / 4;     // 4-col groups
    constexpr int RG    = 256 / QUADS;  // row-groups
    constexpr int R     = ROWS / RG;    // rows per thread
    __shared__ float xs[ROWS * K];
    const int row0 = blockIdx.x * ROWS;

    if (row0 + ROWS <= nrows) {
        const float4* src = (const float4*)(X + (size_t)row0 * K);
        float4* dst = (float4*)xs;
        for (int i = threadIdx.x; i < ROWS * K / 4; i += 256) dst[i] = src[i];
    } else {
        for (int i = threadIdx.x; i < ROWS * K; i += 256) {
            int r = i / K, gr = row0 + r;
            xs[i] = (gr < nrows) ? X[(size_t)gr * K + (i % K)] : 0.f;
        }
    }
    __syncthreads();

    const int q  = threadIdx.x % QUADS;
    const int rg = threadIdx.x / QUADS;
    float acc[R][4];
#pragma unroll
    for (int i = 0; i < R; i++)
#pragma unroll
        for (int c = 0; c < 4; c++) acc[i][c] = 0.f;

    const float* wp = W + 4 * q;
    for (int k4 = 0; k4 < K / 4; k4++) {
        float4 xr[R];
#pragma unroll
        for (int i = 0; i < R; i++)
            xr[i] = *(const float4*)&xs[(rg * R + i) * K + 4 * k4];
#pragma unroll
        for (int kk = 0; kk < 4; kk++) {
            float4 wq = *(const float4*)(wp + (size_t)(4 * k4 + kk) * NOUT);
#pragma unroll
            for (int i = 0; i < R; i++) {
                float xv = (kk == 0) ? xr[i].x : (kk == 1) ? xr[i].y : (kk == 2) ? xr[i].z : xr[i].w;
                acc[i][0] += xv * wq.x;
                acc[i][1] += xv * wq.y;
                acc[i][2] += xv * wq.z;
                acc[i][3] += xv * wq.w;
            }
        }
    }

    const int h = q >> 3;                       // 8 quads per 32-ch head
    float4 asv = *(const float4*)(As + h * 32 + 4 * (q & 7));
    float4 adv = *(const float4*)(Ad + h * 32 + 4 * (q & 7));
#pragma unroll
    for (int i = 0; i < R; i++) {
        int gr = row0 + rg * R + i;
        float s1 = acc[i][0] * asv.x + acc[i][1] * asv.y + acc[i][2] * asv.z + acc[i][3] * asv.w;
        float s2 = acc[i][0] * adv.x + acc[i][1] * adv.y + acc[i][2] * adv.z + acc[i][3] * adv.w;
        s1 += __shfl_xor(s1, 1); s1 += __shfl_xor(s1, 2); s1 += __shfl_xor(s1, 4);
        s2 += __shfl_xor(s2, 1); s2 += __shfl_xor(s2, 2); s2 += __shfl_xor(s2, 4);
        if (gr < nrows) {
            ushort4 hb;
            hb.x = f2bf(acc[i][0]); hb.y = f2bf(acc[i][1]);
            hb.z = f2bf(acc[i][2]); hb.w = f2bf(acc[i][3]);
            *(ushort4*)(Hb + (size_t)gr * NOUT + 4 * q) = hb;
            if ((q & 7) == 0) {
                esrc[gr * Hh + h] = s1;
                edst[gr * Hh + h] = s2;
            }
        }
    }
}

// ---------------- per-(node,head): segment max + 1/exp-sum ----------------
template<int Hh>
__global__ void node_ms2_k(const int* __restrict__ rowptr, const int* __restrict__ cnt,
                           const int* __restrict__ csr_src,
                           const float* __restrict__ esrc, const float* __restrict__ edst,
                           float* __restrict__ mbuf, float* __restrict__ invbuf, int n) {
    int gid = blockIdx.x * blockDim.x + threadIdx.x;
    if (gid >= n * Hh) return;
    int node = gid / Hh, h = gid % Hh;
    int ro = rowptr[node], deg = cnt[node];
    float ed = edst[gid];
    float mx = -1e38f;
    for (int j = 0; j < deg; j++) {
        int sv = csr_src[ro + j];
        float v = esrc[sv * Hh + h] + ed;
        v = (v >= 0.f) ? v : NEG_SLOPE * v;
        mx = fmaxf(mx, v);
    }
    float sum = 0.f;
    for (int j = 0; j < deg; j++) {
        int sv = csr_src[ro + j];
        float v = esrc[sv * Hh + h] + ed;
        v = (v >= 0.f) ? v : NEG_SLOPE * v;
        sum += __expf(v - mx);
    }
    mbuf[gid] = mx;
    invbuf[gid] = 1.f / (sum + 1e-16f);
}

// ---------------- gather-aggregate, alpha on-the-fly, bf16 payload ----------------
__device__ inline void acc_bf8(float* acc, float a, uint4 p) {
    unsigned int u[4] = {p.x, p.y, p.z, p.w};
#pragma unroll
    for (int w = 0; w < 4; w++) {
        float lo = __uint_as_float(u[w] << 16);
        float hi = __uint_as_float(u[w] & 0xffff0000u);
        acc[2 * w + 0] += a * lo;
        acc[2 * w + 1] += a * hi;
    }
}

template<int HC, int Hh, bool OUT_BF16>
__global__ __launch_bounds__(256) void aggr_fly(const int* __restrict__ rowptr, const int* __restrict__ cnt,
                                                const int* __restrict__ csr_src,
                                                const float* __restrict__ esrc, const float* __restrict__ edst,
                                                const float* __restrict__ mbuf, const float* __restrict__ invbuf,
                                                const unsigned short* __restrict__ Hb,
                                                const float* __restrict__ bias,
                                                float* __restrict__ OutF, unsigned short* __restrict__ OutB,
                                                int n) {
    constexpr int TPN = HC / 8;        // threads per node (8 ch each)
    constexpr int NPB = 256 / TPN;
    int node = blockIdx.x * NPB + threadIdx.x / TPN;
    if (node >= n) return;
    int t = threadIdx.x % TPN;
    int h = (t * 8) >> 5;
    int ro = rowptr[node], deg = cnt[node];
    int nh = node * Hh + h;
    float ed = edst[nh], m = mbuf[nh], inv = invbuf[nh];
    float acc[8];
#pragma unroll
    for (int c = 0; c < 8; c++) acc[c] = 0.f;

    int j = 0;
    for (; j + 4 <= deg; j += 4) {
        int s0 = csr_src[ro + j + 0], s1 = csr_src[ro + j + 1];
        int s2 = csr_src[ro + j + 2], s3 = csr_src[ro + j + 3];
        float v0 = esrc[s0 * Hh + h] + ed, v1 = esrc[s1 * Hh + h] + ed;
        float v2 = esrc[s2 * Hh + h] + ed, v3 = esrc[s3 * Hh + h] + ed;
        v0 = (v0 >= 0.f) ? v0 : NEG_SLOPE * v0;
        v1 = (v1 >= 0.f) ? v1 : NEG_SLOPE * v1;
        v2 = (v2 >= 0.f) ? v2 : NEG_SLOPE * v2;
        v3 = (v3 >= 0.f) ? v3 : NEG_SLOPE * v3;
        float a0 = __expf(v0 - m) * inv, a1 = __expf(v1 - m) * inv;
        float a2 = __expf(v2 - m) * inv, a3 = __expf(v3 - m) * inv;
        uint4 p0 = *(const uint4*)(Hb + (size_t)s0 * HC + 8 * t);
        uint4 p1 = *(const uint4*)(Hb + (size_t)s1 * HC + 8 * t);
        uint4 p2 = *(const uint4*)(Hb + (size_t)s2 * HC + 8 * t);
        uint4 p3 = *(const uint4*)(Hb + (size_t)s3 * HC + 8 * t);
        acc_bf8(acc, a0, p0);
        acc_bf8(acc, a1, p1);
        acc_bf8(acc, a2, p2);
        acc_bf8(acc, a3, p3);
    }
    for (; j < deg; j++) {
        int s0 = csr_src[ro + j];
        float v0 = esrc[s0 * Hh + h] + ed;
        v0 = (v0 >= 0.f) ? v0 : NEG_SLOPE * v0;
        float a0 = __expf(v0 - m) * inv;
        uint4 p0 = *(const uint4*)(Hb + (size_t)s0 * HC + 8 * t);
        acc_bf8(acc, a0, p0);
    }

#pragma unroll
    for (int c = 0; c < 8; c++) {
        float v = acc[c] + bias[8 * t + c];
        acc[c] = v > 0.f ? v : 0.f;
    }
    if (OUT_BF16) {
        uint4 o;
        unsigned int* op = (unsigned int*)&o;
#pragma unroll
        for (int w = 0; w < 4; w++)
            op[w] = (unsigned int)f2bf(acc[2 * w]) | ((unsigned int)f2bf(acc[2 * w + 1]) << 16);
        *(uint4*)(OutB + (size_t)node * HC + 8 * t) = o;
    } else {
        float4 o0 = make_float4(acc[0], acc[1], acc[2], acc[3]);
        float4 o1 = make_float4(acc[4], acc[5], acc[6], acc[7]);
        *(float4*)(OutF + (size_t)node * HC + 8 * t + 0) = o0;
        *(float4*)(OutF + (size_t)node * HC + 8 * t + 4) = o1;
    }
}

// ---------------- edge predictor (bf16 h3) ----------------
__device__ inline float dot8(uint4 p, const float* __restrict__ w) {
    unsigned int u[4] = {p.x, p.y, p.z, p.w};
    float s = 0.f;
#pragma unroll
    for (int k = 0; k < 4; k++) {
        float lo = __uint_as_float(u[k] << 16);
        float hi = __uint_as_float(u[k] & 0xffff0000u);
        s += lo * w[2 * k] + hi * w[2 * k + 1];
    }
    return s;
}

__global__ void predict_k(const int* __restrict__ ei, const unsigned short* __restrict__ H3,
                          const float* __restrict__ Wp, const float* __restrict__ bp,
                          float* __restrict__ out, int Eo) {
    int e = blockIdx.x * blockDim.x + threadIdx.x;
    if (e >= Eo) return;
    int sv = ei[e], dv = ei[Eo + e];
    const uint4* hs = (const uint4*)(H3 + (size_t)sv * 32);
    const uint4* hd = (const uint4*)(H3 + (size_t)dv * 32);
    float acc = bp[0];
#pragma unroll
    for (int q = 0; q < 4; q++) acc += dot8(hs[q], Wp + 8 * q);
#pragma unroll
    for (int q = 0; q < 4; q++) acc += dot8(hd[q], Wp + 32 + 8 * q);
    float sg = 1.f / (1.f + __expf(-acc));
    out[e] = sg * 4.f + 1.f;
}

extern "C" void kernel_launch(void* const* d_in, const int* in_sizes, int n_in,
                              void* d_out, int out_size, void* d_ws, size_t ws_size,
                              hipStream_t stream) {
    const float* x   = (const float*)d_in[0];
    const int*   ei  = (const int*)  d_in[1];
    const float* W1  = (const float*)d_in[2];
    const float* as1 = (const float*)d_in[3];
    const float* ad1 = (const float*)d_in[4];
    const float* b1  = (const float*)d_in[5];
    const float* W2  = (const float*)d_in[6];
    const float* as2 = (const float*)d_in[7];
    const float* ad2 = (const float*)d_in[8];
    const float* b2  = (const float*)d_in[9];
    const float* W3  = (const float*)d_in[10];
    const float* as3 = (const float*)d_in[11];
    const float* ad3 = (const float*)d_in[12];
    const float* b3  = (const float*)d_in[13];
    const float* Wp  = (const float*)d_in[14];
    const float* bp  = (const float*)d_in[15];
    float* outp = (float*)d_out;

    const int n    = in_sizes[0] / 128;   // 50000
    const int Eo   = in_sizes[1] / 2;     // 800000
    const int Eext = Eo + n;              // 850000

    char* base = (char*)d_ws;
    float* hB            = (float*)base;                       base += (size_t)n * 256 * 4;
    unsigned short* hAb  = (unsigned short*)base;              base += (size_t)n * 256 * 2;
    unsigned short* h3b  = (unsigned short*)base;              base += (size_t)n * 32 * 2;
    float* esrc          = (float*)base;                       base += (size_t)n * 8 * 4;
    float* edst          = (float*)base;                       base += (size_t)n * 8 * 4;
    float* mbuf          = (float*)base;                       base += (size_t)n * 8 * 4;
    float* invbuf        = (float*)base;                       base += (size_t)n * 8 * 4;
    int* cnt             = (int*)base;                         base += (size_t)n * 4;
    int* rowptr          = (int*)base;                         base += (size_t)n * 4;
    int* cursors         = (int*)base;                         base += (size_t)n * 4;
    int* csr             = (int*)base;                         base += (size_t)Eext * 4;
    int* csr_src         = (int*)base;                         base += (size_t)Eext * 4;
    int* bsum            = (int*)base;

    const int TB = 256;
    auto nb = [](int tot, int tb) { return (tot + tb - 1) / tb; };

    // ---------------- CSR build (dst-sorted) ----------------
    fill_i<<<nb(n, TB), TB, 0, stream>>>(cnt, 0, n);
    hist_k<<<nb(Eext, TB), TB, 0, stream>>>(ei, cnt, Eo, Eext);
    int nChunks = (n + 1023) / 1024;
    scan1_k<<<nChunks, 256, 0, stream>>>(cnt, rowptr, bsum, n);
    scan2_k<<<1, 64, 0, stream>>>(bsum, nChunks);
    scan3_k<<<nb(n, TB), TB, 0, stream>>>(rowptr, cursors, bsum, n);
    scatter_k<<<nb(Eext, TB), TB, 0, stream>>>(ei, cursors, csr, Eo, Eext);
    sort_k<<<nb(n, TB), TB, 0, stream>>>(rowptr, cnt, csr, ei, csr_src, n, Eo);

    // ---------------- Layer 1: K=128, H=8, HC=256 ----------------
    gemm_fused<128, 256, 16, 8><<<nb(n, 16), 256, 0, stream>>>(x, W1, as1, ad1, hAb, esrc, edst, n);
    node_ms2_k<8><<<nb(n * 8, TB), TB, 0, stream>>>(rowptr, cnt, csr_src, esrc, edst, mbuf, invbuf, n);
    aggr_fly<256, 8, false><<<nb(n * 32, TB), TB, 0, stream>>>(rowptr, cnt, csr_src, esrc, edst, mbuf, invbuf, hAb, b1, hB, nullptr, n);

    // ---------------- Layer 2: K=256, H=4, HC=128 ----------------
    gemm_fused<256, 128, 16, 4><<<nb(n, 16), 256, 0, stream>>>(hB, W2, as2, ad2, hAb, esrc, edst, n);
    node_ms2_k<4><<<nb(n * 4, TB), TB, 0, stream>>>(rowptr, cnt, csr_src, esrc, edst, mbuf, invbuf, n);
    aggr_fly<128, 4, false><<<nb(n * 16, TB), TB, 0, stream>>>(rowptr, cnt, csr_src, esrc, edst, mbuf, invbuf, hAb, b2, hB, nullptr, n);

    // ---------------- Layer 3: K=128, H=1, HC=32 ----------------
    gemm_fused<128, 32, 32, 1><<<nb(n, 32), 256, 0, stream>>>(hB, W3, as3, ad3, hAb, esrc, edst, n);
    node_ms2_k<1><<<nb(n, TB), TB, 0, stream>>>(rowptr, cnt, csr_src, esrc, edst, mbuf, invbuf, n);
    aggr_fly<32, 1, true><<<nb(n * 4, TB), TB, 0, stream>>>(rowptr, cnt, csr_src, esrc, edst, mbuf, invbuf, hAb, b3, nullptr, h3b, n);

    // ---------------- predictor ----------------
    predict_k<<<nb(Eo, TB), TB, 0, stream>>>(ei, h3b, Wp, bp, outp, Eo);
}

// Round 5
// 424.064 us; speedup vs baseline: 12.3273x; 1.3028x over previous
//
#include <hip/hip_runtime.h>

#define NEG_SLOPE 0.2f

typedef __attribute__((ext_vector_type(8))) short bf16x8;
typedef __attribute__((ext_vector_type(4))) float f32x4;

__device__ inline unsigned short f2bf(float f) {
    unsigned int u = __float_as_uint(f);
    unsigned int r = (u + 0x7fffu + ((u >> 16) & 1u)) >> 16;
    return (unsigned short)r;
}

// ---------------- fills ----------------
__global__ void fill_i(int* __restrict__ p, int v, int count) {
    int i = blockIdx.x * blockDim.x + threadIdx.x;
    if (i < count) p[i] = v;
}

// ---------------- prep: f32 -> bf16 (vectorized) ----------------
__global__ void xprep_k(const float* __restrict__ in, unsigned short* __restrict__ out, int count4) {
    int i = blockIdx.x * blockDim.x + threadIdx.x;
    if (i >= count4) return;
    float4 v = ((const float4*)in)[i];
    ushort4 o;
    o.x = f2bf(v.x); o.y = f2bf(v.y); o.z = f2bf(v.z); o.w = f2bf(v.w);
    ((ushort4*)out)[i] = o;
}

// ---------------- prep: W[K][NOUT] f32 -> Wl[kc][n] chunk-major bf16 ----------------
// chunk (kc,n) holds bf16 of W[kc*8 .. kc*8+8)[n]  (8 consecutive k of column n)
__global__ void wprep_k(const float* __restrict__ W, unsigned short* __restrict__ Wl, int K, int NOUT) {
    int gid = blockIdx.x * blockDim.x + threadIdx.x;
    int total = (K / 8) * NOUT;
    if (gid >= total) return;
    int kc = gid / NOUT, nn = gid % NOUT;
    unsigned int w[4];
#pragma unroll
    for (int p = 0; p < 4; p++) {
        unsigned int lo = f2bf(W[(size_t)(kc * 8 + 2 * p + 0) * NOUT + nn]);
        unsigned int hi = f2bf(W[(size_t)(kc * 8 + 2 * p + 1) * NOUT + nn]);
        w[p] = lo | (hi << 16);
    }
    uint4 o; o.x = w[0]; o.y = w[1]; o.z = w[2]; o.w = w[3];
    ((uint4*)Wl)[gid] = o;
}

// ---------------- CSR build ----------------
__global__ void hist_k(const int* __restrict__ ei, int* __restrict__ cnt, int Eo, int Eext) {
    int e = blockIdx.x * blockDim.x + threadIdx.x;
    if (e >= Eext) return;
    int dv = (e < Eo) ? ei[Eo + e] : (e - Eo);
    atomicAdd(&cnt[dv], 1);
}

__global__ __launch_bounds__(256) void scan1_k(const int* __restrict__ cnt, int* __restrict__ rowptr,
                                               int* __restrict__ bsum, int n) {
    __shared__ int ts[256];
    int tid = threadIdx.x;
    int base = blockIdx.x * 1024 + tid * 4;
    int v0 = (base + 0 < n) ? cnt[base + 0] : 0;
    int v1 = (base + 1 < n) ? cnt[base + 1] : 0;
    int v2 = (base + 2 < n) ? cnt[base + 2] : 0;
    int v3 = (base + 3 < n) ? cnt[base + 3] : 0;
    int e1 = v0, e2 = e1 + v1, e3 = e2 + v2, tot = e3 + v3;
    ts[tid] = tot;
    __syncthreads();
    for (int off = 1; off < 256; off <<= 1) {
        int x = (tid >= off) ? ts[tid - off] : 0;
        __syncthreads();
        ts[tid] += x;
        __syncthreads();
    }
    int excl = ts[tid] - tot;
    if (base + 0 < n) rowptr[base + 0] = excl;
    if (base + 1 < n) rowptr[base + 1] = excl + e1;
    if (base + 2 < n) rowptr[base + 2] = excl + e2;
    if (base + 3 < n) rowptr[base + 3] = excl + e3;
    if (tid == 255) bsum[blockIdx.x] = ts[255];
}

__global__ void scan2_k(int* __restrict__ bsum, int nb) {
    if (threadIdx.x == 0 && blockIdx.x == 0) {
        int run = 0;
        for (int i = 0; i < nb; i++) { int t = bsum[i]; bsum[i] = run; run += t; }
    }
}

__global__ void scan3_k(int* __restrict__ rowptr, int* __restrict__ cursors,
                        const int* __restrict__ bsum, int n) {
    int gid = blockIdx.x * blockDim.x + threadIdx.x;
    if (gid >= n) return;
    int v = rowptr[gid] + bsum[gid >> 10];
    rowptr[gid] = v;
    cursors[gid] = v;
}

__global__ void scatter_k(const int* __restrict__ ei, int* __restrict__ cursors,
                          int* __restrict__ csr, int Eo, int Eext) {
    int e = blockIdx.x * blockDim.x + threadIdx.x;
    if (e >= Eext) return;
    int dv = (e < Eo) ? ei[Eo + e] : (e - Eo);
    int idx = atomicAdd(&cursors[dv], 1);
    csr[idx] = e;
}

__global__ void sort_k(const int* __restrict__ rowptr, const int* __restrict__ cnt,
                       int* __restrict__ csr, const int* __restrict__ ei,
                       int* __restrict__ csr_src, int n, int Eo) {
    int node = blockIdx.x * blockDim.x + threadIdx.x;
    if (node >= n) return;
    int ro = rowptr[node], deg = cnt[node];
    for (int i = 1; i < deg; i++) {
        int key = csr[ro + i];
        int j = i - 1;
        while (j >= 0 && csr[ro + j] > key) { csr[ro + j + 1] = csr[ro + j]; j--; }
        csr[ro + j + 1] = key;
    }
    for (int i = 0; i < deg; i++) {
        int eid = csr[ro + i];
        csr_src[ro + i] = (eid < Eo) ? ei[eid] : node;
    }
}

// ---------------- MFMA GEMM (bf16 in, bf16 out) + fused attention scores ----------------
// Hb[M][NOUT] = Xb[M][K] @ W;  esrc/edst[M][Hh] = per-head dots with As/Ad (f32 acc).
// Wl is chunk-major: chunk (kc,n) = 8 consecutive k of W column n.
// Per MFMA: D = mfma(Wtile_frag, Xt_frag) -> lane owns node m = m0+(lane&15),
// channels t*16 + (lane>>4)*4 + [0..4).
template<int K, int NOUT, int Hh>
__global__ __launch_bounds__(256) void gemm_mfma(const unsigned short* __restrict__ Xb,
                                                 const unsigned short* __restrict__ Wl,
                                                 const float* __restrict__ As,
                                                 const float* __restrict__ Ad,
                                                 unsigned short* __restrict__ Hb,
                                                 float* __restrict__ esrc,
                                                 float* __restrict__ edst, int M) {
    constexpr int NT    = NOUT / 16;              // n-tiles
    constexpr int TP    = (NT < 8) ? NT : 8;      // tiles per pass
    constexpr int NPASS = NT / TP;
    constexpr int NCH   = K / 8;                  // 8-elem chunks per row
    constexpr int HPP   = (TP * 16) / 32;         // heads per pass

    __shared__ unsigned short wlds[K * NOUT];

    // stage Wl (linear, conflict-free by construction)
    {
        const uint4* src = (const uint4*)Wl;
        uint4* dst = (uint4*)wlds;
        for (int i = threadIdx.x; i < K * NOUT / 8; i += 256) dst[i] = src[i];
    }
    __syncthreads();

    const int lane = threadIdx.x & 63;
    const int wid  = threadIdx.x >> 6;
    const int l15  = lane & 15;
    const int g4   = lane >> 4;                   // 0..3
    const int m0   = blockIdx.x * 128 + wid * 32;
    const int m_s[2]  = { m0 + l15, m0 + 16 + l15 };
    const int mi[2]   = { min(m_s[0], M - 1), min(m_s[1], M - 1) };

    const bf16x8* xb8 = (const bf16x8*)Xb;
    const bf16x8* wl8 = (const bf16x8*)wlds;

    for (int pass = 0; pass < NPASS; ++pass) {
        f32x4 acc[TP][2];
#pragma unroll
        for (int tt = 0; tt < TP; ++tt)
#pragma unroll
            for (int s = 0; s < 2; ++s) acc[tt][s] = (f32x4)0.f;

        for (int ks = 0; ks < K / 32; ++ks) {
            int kc = ks * 4 + g4;
            bf16x8 a0 = xb8[(size_t)mi[0] * NCH + kc];
            bf16x8 a1 = xb8[(size_t)mi[1] * NCH + kc];
#pragma unroll
            for (int tt = 0; tt < TP; ++tt) {
                int nn = (pass * TP + tt) * 16 + l15;
                bf16x8 b = wl8[kc * NOUT + nn];
                acc[tt][0] = __builtin_amdgcn_mfma_f32_16x16x32_bf16(b, a0, acc[tt][0], 0, 0, 0);
                acc[tt][1] = __builtin_amdgcn_mfma_f32_16x16x32_bf16(b, a1, acc[tt][1], 0, 0, 0);
            }
        }

        // epilogue: bf16 store + fused per-head score partials
        float s1[2][HPP], s2[2][HPP];
#pragma unroll
        for (int s = 0; s < 2; ++s)
#pragma unroll
            for (int hh = 0; hh < HPP; ++hh) { s1[s][hh] = 0.f; s2[s][hh] = 0.f; }

#pragma unroll
        for (int tt = 0; tt < TP; ++tt) {
            int t  = pass * TP + tt;
            int ch = t * 16 + g4 * 4;
            float4 asv = *(const float4*)(As + ch);
            float4 adv = *(const float4*)(Ad + ch);
            int hh = tt >> 1;
#pragma unroll
            for (int s = 0; s < 2; ++s) {
                f32x4 a = acc[tt][s];
                s1[s][hh] += a[0] * asv.x + a[1] * asv.y + a[2] * asv.z + a[3] * asv.w;
                s2[s][hh] += a[0] * adv.x + a[1] * adv.y + a[2] * adv.z + a[3] * adv.w;
                int m = m_s[s];
                if (m < M) {
                    ushort4 o;
                    o.x = f2bf(a[0]); o.y = f2bf(a[1]); o.z = f2bf(a[2]); o.w = f2bf(a[3]);
                    *(ushort4*)(Hb + (size_t)m * NOUT + ch) = o;
                }
            }
        }
#pragma unroll
        for (int s = 0; s < 2; ++s) {
            int m = m_s[s];
#pragma unroll
            for (int hh = 0; hh < HPP; ++hh) {
                float p1 = s1[s][hh], p2 = s2[s][hh];
                p1 += __shfl_xor(p1, 16); p1 += __shfl_xor(p1, 32);
                p2 += __shfl_xor(p2, 16); p2 += __shfl_xor(p2, 32);
                if (g4 == 0 && m < M) {
                    int h = pass * HPP + hh;
                    esrc[m * Hh + h] = p1;
                    edst[m * Hh + h] = p2;
                }
            }
        }
    }
}

// ---------------- per-(node,head): segment max + 1/exp-sum ----------------
template<int Hh>
__global__ void node_ms2_k(const int* __restrict__ rowptr, const int* __restrict__ cnt,
                           const int* __restrict__ csr_src,
                           const float* __restrict__ esrc, const float* __restrict__ edst,
                           float* __restrict__ mbuf, float* __restrict__ invbuf, int n) {
    int gid = blockIdx.x * blockDim.x + threadIdx.x;
    if (gid >= n * Hh) return;
    int node = gid / Hh, h = gid % Hh;
    int ro = rowptr[node], deg = cnt[node];
    float ed = edst[gid];
    float mx = -1e38f;
    for (int j = 0; j < deg; j++) {
        int sv = csr_src[ro + j];
        float v = esrc[sv * Hh + h] + ed;
        v = (v >= 0.f) ? v : NEG_SLOPE * v;
        mx = fmaxf(mx, v);
    }
    float sum = 0.f;
    for (int j = 0; j < deg; j++) {
        int sv = csr_src[ro + j];
        float v = esrc[sv * Hh + h] + ed;
        v = (v >= 0.f) ? v : NEG_SLOPE * v;
        sum += __expf(v - mx);
    }
    mbuf[gid] = mx;
    invbuf[gid] = 1.f / (sum + 1e-16f);
}

// ---------------- gather-aggregate, alpha on-the-fly, bf16 payload + bf16 out ----------------
__device__ inline void acc_bf8(float* acc, float a, uint4 p) {
    unsigned int u[4] = {p.x, p.y, p.z, p.w};
#pragma unroll
    for (int w = 0; w < 4; w++) {
        float lo = __uint_as_float(u[w] << 16);
        float hi = __uint_as_float(u[w] & 0xffff0000u);
        acc[2 * w + 0] += a * lo;
        acc[2 * w + 1] += a * hi;
    }
}

template<int HC, int Hh>
__global__ __launch_bounds__(256) void aggr_fly(const int* __restrict__ rowptr, const int* __restrict__ cnt,
                                                const int* __restrict__ csr_src,
                                                const float* __restrict__ esrc, const float* __restrict__ edst,
                                                const float* __restrict__ mbuf, const float* __restrict__ invbuf,
                                                const unsigned short* __restrict__ Hb,
                                                const float* __restrict__ bias,
                                                unsigned short* __restrict__ OutB, int n) {
    constexpr int TPN = HC / 8;
    constexpr int NPB = 256 / TPN;
    int node = blockIdx.x * NPB + threadIdx.x / TPN;
    if (node >= n) return;
    int t = threadIdx.x % TPN;
    int h = (t * 8) >> 5;
    int ro = rowptr[node], deg = cnt[node];
    int nh = node * Hh + h;
    float ed = edst[nh], m = mbuf[nh], inv = invbuf[nh];
    float acc[8];
#pragma unroll
    for (int c = 0; c < 8; c++) acc[c] = 0.f;

    int j = 0;
    for (; j + 4 <= deg; j += 4) {
        int s0 = csr_src[ro + j + 0], s1 = csr_src[ro + j + 1];
        int s2 = csr_src[ro + j + 2], s3 = csr_src[ro + j + 3];
        float v0 = esrc[s0 * Hh + h] + ed, v1 = esrc[s1 * Hh + h] + ed;
        float v2 = esrc[s2 * Hh + h] + ed, v3 = esrc[s3 * Hh + h] + ed;
        v0 = (v0 >= 0.f) ? v0 : NEG_SLOPE * v0;
        v1 = (v1 >= 0.f) ? v1 : NEG_SLOPE * v1;
        v2 = (v2 >= 0.f) ? v2 : NEG_SLOPE * v2;
        v3 = (v3 >= 0.f) ? v3 : NEG_SLOPE * v3;
        float a0 = __expf(v0 - m) * inv, a1 = __expf(v1 - m) * inv;
        float a2 = __expf(v2 - m) * inv, a3 = __expf(v3 - m) * inv;
        uint4 p0 = *(const uint4*)(Hb + (size_t)s0 * HC + 8 * t);
        uint4 p1 = *(const uint4*)(Hb + (size_t)s1 * HC + 8 * t);
        uint4 p2 = *(const uint4*)(Hb + (size_t)s2 * HC + 8 * t);
        uint4 p3 = *(const uint4*)(Hb + (size_t)s3 * HC + 8 * t);
        acc_bf8(acc, a0, p0);
        acc_bf8(acc, a1, p1);
        acc_bf8(acc, a2, p2);
        acc_bf8(acc, a3, p3);
    }
    for (; j < deg; j++) {
        int s0 = csr_src[ro + j];
        float v0 = esrc[s0 * Hh + h] + ed;
        v0 = (v0 >= 0.f) ? v0 : NEG_SLOPE * v0;
        float a0 = __expf(v0 - m) * inv;
        uint4 p0 = *(const uint4*)(Hb + (size_t)s0 * HC + 8 * t);
        acc_bf8(acc, a0, p0);
    }

    uint4 o;
    unsigned int* op = (unsigned int*)&o;
#pragma unroll
    for (int w = 0; w < 4; w++) {
        float va = acc[2 * w + 0] + bias[8 * t + 2 * w + 0];
        float vb = acc[2 * w + 1] + bias[8 * t + 2 * w + 1];
        va = va > 0.f ? va : 0.f;
        vb = vb > 0.f ? vb : 0.f;
        op[w] = (unsigned int)f2bf(va) | ((unsigned int)f2bf(vb) << 16);
    }
    *(uint4*)(OutB + (size_t)node * HC + 8 * t) = o;
}

// ---------------- edge predictor (bf16 h3) ----------------
__device__ inline float dot8(uint4 p, const float* __restrict__ w) {
    unsigned int u[4] = {p.x, p.y, p.z, p.w};
    float s = 0.f;
#pragma unroll
    for (int k = 0; k < 4; k++) {
        float lo = __uint_as_float(u[k] << 16);
        float hi = __uint_as_float(u[k] & 0xffff0000u);
        s += lo * w[2 * k] + hi * w[2 * k + 1];
    }
    return s;
}

__global__ void predict_k(const int* __restrict__ ei, const unsigned short* __restrict__ H3,
                          const float* __restrict__ Wp, const float* __restrict__ bp,
                          float* __restrict__ out, int Eo) {
    int e = blockIdx.x * blockDim.x + threadIdx.x;
    if (e >= Eo) return;
    int sv = ei[e], dv = ei[Eo + e];
    const uint4* hs = (const uint4*)(H3 + (size_t)sv * 32);
    const uint4* hd = (const uint4*)(H3 + (size_t)dv * 32);
    float acc = bp[0];
#pragma unroll
    for (int q = 0; q < 4; q++) acc += dot8(hs[q], Wp + 8 * q);
#pragma unroll
    for (int q = 0; q < 4; q++) acc += dot8(hd[q], Wp + 32 + 8 * q);
    float sg = 1.f / (1.f + __expf(-acc));
    out[e] = sg * 4.f + 1.f;
}

extern "C" void kernel_launch(void* const* d_in, const int* in_sizes, int n_in,
                              void* d_out, int out_size, void* d_ws, size_t ws_size,
                              hipStream_t stream) {
    const float* x   = (const float*)d_in[0];
    const int*   ei  = (const int*)  d_in[1];
    const float* W1  = (const float*)d_in[2];
    const float* as1 = (const float*)d_in[3];
    const float* ad1 = (const float*)d_in[4];
    const float* b1  = (const float*)d_in[5];
    const float* W2  = (const float*)d_in[6];
    const float* as2 = (const float*)d_in[7];
    const float* ad2 = (const float*)d_in[8];
    const float* b2  = (const float*)d_in[9];
    const float* W3  = (const float*)d_in[10];
    const float* as3 = (const float*)d_in[11];
    const float* ad3 = (const float*)d_in[12];
    const float* b3  = (const float*)d_in[13];
    const float* Wp  = (const float*)d_in[14];
    const float* bp  = (const float*)d_in[15];
    float* outp = (float*)d_out;

    const int n    = in_sizes[0] / 128;   // 50000
    const int Eo   = in_sizes[1] / 2;     // 800000
    const int Eext = Eo + n;              // 850000

    char* base = (char*)d_ws;
    unsigned short* hAb = (unsigned short*)base;   base += (size_t)n * 256 * 2;  // current-layer h (bf16)
    unsigned short* hBb = (unsigned short*)base;   base += (size_t)n * 256 * 2;  // aggregated out (bf16)
    unsigned short* Xb  = (unsigned short*)base;   base += (size_t)n * 128 * 2;  // x in bf16
    unsigned short* h3b = (unsigned short*)base;   base += (size_t)n * 32 * 2;
    unsigned short* Wl1 = (unsigned short*)base;   base += (size_t)128 * 256 * 2;
    unsigned short* Wl2 = (unsigned short*)base;   base += (size_t)256 * 128 * 2;
    unsigned short* Wl3 = (unsigned short*)base;   base += (size_t)128 * 32 * 2;
    float* esrc   = (float*)base;                  base += (size_t)n * 8 * 4;
    float* edst   = (float*)base;                  base += (size_t)n * 8 * 4;
    float* mbuf   = (float*)base;                  base += (size_t)n * 8 * 4;
    float* invbuf = (float*)base;                  base += (size_t)n * 8 * 4;
    int* cnt      = (int*)base;                    base += (size_t)n * 4;
    int* rowptr   = (int*)base;                    base += (size_t)n * 4;
    int* cursors  = (int*)base;                    base += (size_t)n * 4;
    int* csr      = (int*)base;                    base += (size_t)Eext * 4;
    int* csr_src  = (int*)base;                    base += (size_t)Eext * 4;
    int* bsum     = (int*)base;

    const int TB = 256;
    auto nb = [](int tot, int tb) { return (tot + tb - 1) / tb; };

    // ---------------- CSR build (dst-sorted) ----------------
    fill_i<<<nb(n, TB), TB, 0, stream>>>(cnt, 0, n);
    hist_k<<<nb(Eext, TB), TB, 0, stream>>>(ei, cnt, Eo, Eext);
    int nChunks = (n + 1023) / 1024;
    scan1_k<<<nChunks, 256, 0, stream>>>(cnt, rowptr, bsum, n);
    scan2_k<<<1, 64, 0, stream>>>(bsum, nChunks);
    scan3_k<<<nb(n, TB), TB, 0, stream>>>(rowptr, cursors, bsum, n);
    scatter_k<<<nb(Eext, TB), TB, 0, stream>>>(ei, cursors, csr, Eo, Eext);
    sort_k<<<nb(n, TB), TB, 0, stream>>>(rowptr, cnt, csr, ei, csr_src, n, Eo);

    // ---------------- prep: bf16 conversions ----------------
    xprep_k<<<nb(n * 128 / 4, TB), TB, 0, stream>>>(x, Xb, n * 128 / 4);
    wprep_k<<<nb(16 * 256, TB), TB, 0, stream>>>(W1, Wl1, 128, 256);
    wprep_k<<<nb(32 * 128, TB), TB, 0, stream>>>(W2, Wl2, 256, 128);
    wprep_k<<<nb(16 * 32, TB), TB, 0, stream>>>(W3, Wl3, 128, 32);

    // ---------------- Layer 1: K=128, H=8, HC=256 ----------------
    gemm_mfma<128, 256, 8><<<nb(n, 128), 256, 0, stream>>>(Xb, Wl1, as1, ad1, hAb, esrc, edst, n);
    node_ms2_k<8><<<nb(n * 8, TB), TB, 0, stream>>>(rowptr, cnt, csr_src, esrc, edst, mbuf, invbuf, n);
    aggr_fly<256, 8><<<nb(n * 32, TB), TB, 0, stream>>>(rowptr, cnt, csr_src, esrc, edst, mbuf, invbuf, hAb, b1, hBb, n);

    // ---------------- Layer 2: K=256, H=4, HC=128 ----------------
    gemm_mfma<256, 128, 4><<<nb(n, 128), 256, 0, stream>>>(hBb, Wl2, as2, ad2, hAb, esrc, edst, n);
    node_ms2_k<4><<<nb(n * 4, TB), TB, 0, stream>>>(rowptr, cnt, csr_src, esrc, edst, mbuf, invbuf, n);
    aggr_fly<128, 4><<<nb(n * 16, TB), TB, 0, stream>>>(rowptr, cnt, csr_src, esrc, edst, mbuf, invbuf, hAb, b2, hBb, n);

    // ---------------- Layer 3: K=128, H=1, HC=32 ----------------
    gemm_mfma<128, 32, 1><<<nb(n, 128), 256, 0, stream>>>(hBb, Wl3, as3, ad3, hAb, esrc, edst, n);
    node_ms2_k<1><<<nb(n, TB), TB, 0, stream>>>(rowptr, cnt, csr_src, esrc, edst, mbuf, invbuf, n);
    aggr_fly<32, 1><<<nb(n * 4, TB), TB, 0, stream>>>(rowptr, cnt, csr_src, esrc, edst, mbuf, invbuf, hAb, b3, h3b, n);

    // ---------------- predictor ----------------
    predict_k<<<nb(Eo, TB), TB, 0, stream>>>(ei, h3b, Wp, bp, outp, Eo);
}

// Round 6
// 363.962 us; speedup vs baseline: 14.3629x; 1.1651x over previous
//
#include <hip/hip_runtime.h>

#define NEG_SLOPE 0.2f

typedef __attribute__((ext_vector_type(8))) short bf16x8;
typedef __attribute__((ext_vector_type(4))) float f32x4;

__device__ inline unsigned short f2bf(float f) {
    unsigned int u = __float_as_uint(f);
    unsigned int r = (u + 0x7fffu + ((u >> 16) & 1u)) >> 16;
    return (unsigned short)r;
}

// ---------------- fills ----------------
__global__ void fill_i(int* __restrict__ p, int v, int count) {
    int i = blockIdx.x * blockDim.x + threadIdx.x;
    if (i < count) p[i] = v;
}

// ---------------- prep: f32 -> bf16 (vectorized) ----------------
__global__ void xprep_k(const float* __restrict__ in, unsigned short* __restrict__ out, int count4) {
    int i = blockIdx.x * blockDim.x + threadIdx.x;
    if (i >= count4) return;
    float4 v = ((const float4*)in)[i];
    ushort4 o;
    o.x = f2bf(v.x); o.y = f2bf(v.y); o.z = f2bf(v.z); o.w = f2bf(v.w);
    ((ushort4*)out)[i] = o;
}

// ---------------- prep: W[K][NOUT] f32 -> Wl[kc][n] chunk-major bf16 ----------------
__global__ void wprep_k(const float* __restrict__ W, unsigned short* __restrict__ Wl, int K, int NOUT) {
    int gid = blockIdx.x * blockDim.x + threadIdx.x;
    int total = (K / 8) * NOUT;
    if (gid >= total) return;
    int kc = gid / NOUT, nn = gid % NOUT;
    unsigned int w[4];
#pragma unroll
    for (int p = 0; p < 4; p++) {
        unsigned int lo = f2bf(W[(size_t)(kc * 8 + 2 * p + 0) * NOUT + nn]);
        unsigned int hi = f2bf(W[(size_t)(kc * 8 + 2 * p + 1) * NOUT + nn]);
        w[p] = lo | (hi << 16);
    }
    uint4 o; o.x = w[0]; o.y = w[1]; o.z = w[2]; o.w = w[3];
    ((uint4*)Wl)[gid] = o;
}

// ---------------- CSR build ----------------
__global__ void hist_k(const int* __restrict__ ei, int* __restrict__ cnt, int Eo, int Eext) {
    int e = blockIdx.x * blockDim.x + threadIdx.x;
    if (e >= Eext) return;
    int dv = (e < Eo) ? ei[Eo + e] : (e - Eo);
    atomicAdd(&cnt[dv], 1);
}

__global__ __launch_bounds__(256) void scan1_k(const int* __restrict__ cnt, int* __restrict__ rowptr,
                                               int* __restrict__ bsum, int n) {
    __shared__ int ts[256];
    int tid = threadIdx.x;
    int base = blockIdx.x * 1024 + tid * 4;
    int v0 = (base + 0 < n) ? cnt[base + 0] : 0;
    int v1 = (base + 1 < n) ? cnt[base + 1] : 0;
    int v2 = (base + 2 < n) ? cnt[base + 2] : 0;
    int v3 = (base + 3 < n) ? cnt[base + 3] : 0;
    int e1 = v0, e2 = e1 + v1, e3 = e2 + v2, tot = e3 + v3;
    ts[tid] = tot;
    __syncthreads();
    for (int off = 1; off < 256; off <<= 1) {
        int x = (tid >= off) ? ts[tid - off] : 0;
        __syncthreads();
        ts[tid] += x;
        __syncthreads();
    }
    int excl = ts[tid] - tot;
    if (base + 0 < n) rowptr[base + 0] = excl;
    if (base + 1 < n) rowptr[base + 1] = excl + e1;
    if (base + 2 < n) rowptr[base + 2] = excl + e2;
    if (base + 3 < n) rowptr[base + 3] = excl + e3;
    if (tid == 255) bsum[blockIdx.x] = ts[255];
}

__global__ void scan2_k(int* __restrict__ bsum, int nb) {
    if (threadIdx.x == 0 && blockIdx.x == 0) {
        int run = 0;
        for (int i = 0; i < nb; i++) { int t = bsum[i]; bsum[i] = run; run += t; }
    }
}

__global__ void scan3_k(int* __restrict__ rowptr, int* __restrict__ cursors,
                        const int* __restrict__ bsum, int n) {
    int gid = blockIdx.x * blockDim.x + threadIdx.x;
    if (gid >= n) return;
    int v = rowptr[gid] + bsum[gid >> 10];
    rowptr[gid] = v;
    cursors[gid] = v;
}

__global__ void scatter_k(const int* __restrict__ ei, int* __restrict__ cursors,
                          int* __restrict__ csr, int Eo, int Eext) {
    int e = blockIdx.x * blockDim.x + threadIdx.x;
    if (e >= Eext) return;
    int dv = (e < Eo) ? ei[Eo + e] : (e - Eo);
    int idx = atomicAdd(&cursors[dv], 1);
    csr[idx] = e;
}

__global__ void sort_k(const int* __restrict__ rowptr, const int* __restrict__ cnt,
                       int* __restrict__ csr, const int* __restrict__ ei,
                       int* __restrict__ csr_src, int n, int Eo) {
    int node = blockIdx.x * blockDim.x + threadIdx.x;
    if (node >= n) return;
    int ro = rowptr[node], deg = cnt[node];
    for (int i = 1; i < deg; i++) {
        int key = csr[ro + i];
        int j = i - 1;
        while (j >= 0 && csr[ro + j] > key) { csr[ro + j + 1] = csr[ro + j]; j--; }
        csr[ro + j + 1] = key;
    }
    for (int i = 0; i < deg; i++) {
        int eid = csr[ro + i];
        csr_src[ro + i] = (eid < Eo) ? ei[eid] : node;
    }
}

// ---------------- MFMA GEMM (bf16 in, bf16 out) + fused attention scores ----------------
template<int K, int NOUT, int Hh>
__global__ __launch_bounds__(256) void gemm_mfma(const unsigned short* __restrict__ Xb,
                                                 const unsigned short* __restrict__ Wl,
                                                 const float* __restrict__ As,
                                                 const float* __restrict__ Ad,
                                                 unsigned short* __restrict__ Hb,
                                                 float* __restrict__ esrc,
                                                 float* __restrict__ edst, int M) {
    constexpr int NT    = NOUT / 16;
    constexpr int TP    = (NT < 8) ? NT : 8;
    constexpr int NPASS = NT / TP;
    constexpr int NCH   = K / 8;
    constexpr int HPP   = (TP * 16) / 32;

    __shared__ unsigned short wlds[K * NOUT];
    {
        const uint4* src = (const uint4*)Wl;
        uint4* dst = (uint4*)wlds;
        for (int i = threadIdx.x; i < K * NOUT / 8; i += 256) dst[i] = src[i];
    }
    __syncthreads();

    const int lane = threadIdx.x & 63;
    const int wid  = threadIdx.x >> 6;
    const int l15  = lane & 15;
    const int g4   = lane >> 4;
    const int m0   = blockIdx.x * 128 + wid * 32;
    const int m_s[2]  = { m0 + l15, m0 + 16 + l15 };
    const int mi[2]   = { min(m_s[0], M - 1), min(m_s[1], M - 1) };

    const bf16x8* xb8 = (const bf16x8*)Xb;
    const bf16x8* wl8 = (const bf16x8*)wlds;

    for (int pass = 0; pass < NPASS; ++pass) {
        f32x4 acc[TP][2];
#pragma unroll
        for (int tt = 0; tt < TP; ++tt)
#pragma unroll
            for (int s = 0; s < 2; ++s) acc[tt][s] = (f32x4)0.f;

        for (int ks = 0; ks < K / 32; ++ks) {
            int kc = ks * 4 + g4;
            bf16x8 a0 = xb8[(size_t)mi[0] * NCH + kc];
            bf16x8 a1 = xb8[(size_t)mi[1] * NCH + kc];
#pragma unroll
            for (int tt = 0; tt < TP; ++tt) {
                int nn = (pass * TP + tt) * 16 + l15;
                bf16x8 b = wl8[kc * NOUT + nn];
                acc[tt][0] = __builtin_amdgcn_mfma_f32_16x16x32_bf16(b, a0, acc[tt][0], 0, 0, 0);
                acc[tt][1] = __builtin_amdgcn_mfma_f32_16x16x32_bf16(b, a1, acc[tt][1], 0, 0, 0);
            }
        }

        float s1[2][HPP], s2[2][HPP];
#pragma unroll
        for (int s = 0; s < 2; ++s)
#pragma unroll
            for (int hh = 0; hh < HPP; ++hh) { s1[s][hh] = 0.f; s2[s][hh] = 0.f; }

#pragma unroll
        for (int tt = 0; tt < TP; ++tt) {
            int t  = pass * TP + tt;
            int ch = t * 16 + g4 * 4;
            float4 asv = *(const float4*)(As + ch);
            float4 adv = *(const float4*)(Ad + ch);
            int hh = tt >> 1;
#pragma unroll
            for (int s = 0; s < 2; ++s) {
                f32x4 a = acc[tt][s];
                s1[s][hh] += a[0] * asv.x + a[1] * asv.y + a[2] * asv.z + a[3] * asv.w;
                s2[s][hh] += a[0] * adv.x + a[1] * adv.y + a[2] * adv.z + a[3] * adv.w;
                int m = m_s[s];
                if (m < M) {
                    ushort4 o;
                    o.x = f2bf(a[0]); o.y = f2bf(a[1]); o.z = f2bf(a[2]); o.w = f2bf(a[3]);
                    *(ushort4*)(Hb + (size_t)m * NOUT + ch) = o;
                }
            }
        }
#pragma unroll
        for (int s = 0; s < 2; ++s) {
            int m = m_s[s];
#pragma unroll
            for (int hh = 0; hh < HPP; ++hh) {
                float p1 = s1[s][hh], p2 = s2[s][hh];
                p1 += __shfl_xor(p1, 16); p1 += __shfl_xor(p1, 32);
                p2 += __shfl_xor(p2, 16); p2 += __shfl_xor(p2, 32);
                if (g4 == 0 && m < M) {
                    int h = pass * HPP + hh;
                    esrc[m * Hh + h] = p1;
                    edst[m * Hh + h] = p2;
                }
            }
        }
    }
}

// ---------------- fused segment-softmax + gather-aggregate ----------------
__device__ inline void acc_bf8(float* acc, float a, uint4 p) {
    unsigned int u[4] = {p.x, p.y, p.z, p.w};
#pragma unroll
    for (int w = 0; w < 4; w++) {
        float lo = __uint_as_float(u[w] << 16);
        float hi = __uint_as_float(u[w] & 0xffff0000u);
        acc[2 * w + 0] += a * lo;
        acc[2 * w + 1] += a * hi;
    }
}

// pass A: distributed max over 4-lane subgroup; pass B: payload gather + exp-sum.
// PRED epilogue: bias+relu+dot(Wp) -> psrc/pdst (h3 never materialized).
template<int HC, int Hh, bool PRED>
__global__ __launch_bounds__(256) void aggr_fused(const int* __restrict__ rowptr, const int* __restrict__ cnt,
                                                  const int* __restrict__ csr_src,
                                                  const float* __restrict__ esrc, const float* __restrict__ edst,
                                                  const unsigned short* __restrict__ Hb,
                                                  const float* __restrict__ bias,
                                                  unsigned short* __restrict__ OutB,
                                                  float* __restrict__ psrc, float* __restrict__ pdst,
                                                  const float* __restrict__ Wp, int n) {
    constexpr int TPN = HC / 8;
    constexpr int NPB = 256 / TPN;
    int node = blockIdx.x * NPB + threadIdx.x / TPN;
    if (node >= n) return;
    int t = threadIdx.x % TPN;
    int h = t >> 2;
    int ro = rowptr[node], deg = cnt[node];
    float ed = edst[node * Hh + h];

    // ---- pass A: segment max, edges split across the 4-lane subgroup ----
    int sub = t & 3;
    float mx = -1e38f;
    for (int j = sub; j < deg; j += 4) {
        int sv = csr_src[ro + j];
        float v = esrc[sv * Hh + h] + ed;
        v = (v >= 0.f) ? v : NEG_SLOPE * v;
        mx = fmaxf(mx, v);
    }
    mx = fmaxf(mx, __shfl_xor(mx, 1));
    mx = fmaxf(mx, __shfl_xor(mx, 2));

    // ---- pass B: payload gather + exp accumulate ----
    float s = 0.f;
    float acc[8];
#pragma unroll
    for (int c = 0; c < 8; c++) acc[c] = 0.f;

    int j = 0;
    for (; j + 4 <= deg; j += 4) {
        int s0 = csr_src[ro + j + 0], s1 = csr_src[ro + j + 1];
        int s2 = csr_src[ro + j + 2], s3 = csr_src[ro + j + 3];
        float v0 = esrc[s0 * Hh + h] + ed, v1 = esrc[s1 * Hh + h] + ed;
        float v2 = esrc[s2 * Hh + h] + ed, v3 = esrc[s3 * Hh + h] + ed;
        v0 = (v0 >= 0.f) ? v0 : NEG_SLOPE * v0;
        v1 = (v1 >= 0.f) ? v1 : NEG_SLOPE * v1;
        v2 = (v2 >= 0.f) ? v2 : NEG_SLOPE * v2;
        v3 = (v3 >= 0.f) ? v3 : NEG_SLOPE * v3;
        float a0 = __expf(v0 - mx), a1 = __expf(v1 - mx);
        float a2 = __expf(v2 - mx), a3 = __expf(v3 - mx);
        uint4 p0 = *(const uint4*)(Hb + (size_t)s0 * HC + 8 * t);
        uint4 p1 = *(const uint4*)(Hb + (size_t)s1 * HC + 8 * t);
        uint4 p2 = *(const uint4*)(Hb + (size_t)s2 * HC + 8 * t);
        uint4 p3 = *(const uint4*)(Hb + (size_t)s3 * HC + 8 * t);
        s += a0 + a1 + a2 + a3;
        acc_bf8(acc, a0, p0);
        acc_bf8(acc, a1, p1);
        acc_bf8(acc, a2, p2);
        acc_bf8(acc, a3, p3);
    }
    for (; j < deg; j++) {
        int s0 = csr_src[ro + j];
        float v0 = esrc[s0 * Hh + h] + ed;
        v0 = (v0 >= 0.f) ? v0 : NEG_SLOPE * v0;
        float a0 = __expf(v0 - mx);
        uint4 p0 = *(const uint4*)(Hb + (size_t)s0 * HC + 8 * t);
        s += a0;
        acc_bf8(acc, a0, p0);
    }

    float inv = 1.f / (s + 1e-16f);

    if (PRED) {
        float d1 = 0.f, d2 = 0.f;
#pragma unroll
        for (int c = 0; c < 8; c++) {
            float v = acc[c] * inv + bias[8 * t + c];
            v = v > 0.f ? v : 0.f;
            d1 += v * Wp[8 * t + c];
            d2 += v * Wp[32 + 8 * t + c];
        }
        d1 += __shfl_xor(d1, 1); d1 += __shfl_xor(d1, 2);
        d2 += __shfl_xor(d2, 1); d2 += __shfl_xor(d2, 2);
        if (sub == 0) {
            psrc[node] = d1;
            pdst[node] = d2;
        }
    } else {
        uint4 o;
        unsigned int* op = (unsigned int*)&o;
#pragma unroll
        for (int w = 0; w < 4; w++) {
            float va = acc[2 * w + 0] * inv + bias[8 * t + 2 * w + 0];
            float vb = acc[2 * w + 1] * inv + bias[8 * t + 2 * w + 1];
            va = va > 0.f ? va : 0.f;
            vb = vb > 0.f ? vb : 0.f;
            op[w] = (unsigned int)f2bf(va) | ((unsigned int)f2bf(vb) << 16);
        }
        *(uint4*)(OutB + (size_t)node * HC + 8 * t) = o;
    }
}

// ---------------- rank-1 edge predictor ----------------
__global__ void predict2_k(const int* __restrict__ ei, const float* __restrict__ psrc,
                           const float* __restrict__ pdst, const float* __restrict__ bp,
                           float* __restrict__ out, int Eo) {
    int e = blockIdx.x * blockDim.x + threadIdx.x;
    if (e >= Eo) return;
    float acc = psrc[ei[e]] + pdst[ei[Eo + e]] + bp[0];
    float sg = 1.f / (1.f + __expf(-acc));
    out[e] = sg * 4.f + 1.f;
}

extern "C" void kernel_launch(void* const* d_in, const int* in_sizes, int n_in,
                              void* d_out, int out_size, void* d_ws, size_t ws_size,
                              hipStream_t stream) {
    const float* x   = (const float*)d_in[0];
    const int*   ei  = (const int*)  d_in[1];
    const float* W1  = (const float*)d_in[2];
    const float* as1 = (const float*)d_in[3];
    const float* ad1 = (const float*)d_in[4];
    const float* b1  = (const float*)d_in[5];
    const float* W2  = (const float*)d_in[6];
    const float* as2 = (const float*)d_in[7];
    const float* ad2 = (const float*)d_in[8];
    const float* b2  = (const float*)d_in[9];
    const float* W3  = (const float*)d_in[10];
    const float* as3 = (const float*)d_in[11];
    const float* ad3 = (const float*)d_in[12];
    const float* b3  = (const float*)d_in[13];
    const float* Wp  = (const float*)d_in[14];
    const float* bp  = (const float*)d_in[15];
    float* outp = (float*)d_out;

    const int n    = in_sizes[0] / 128;   // 50000
    const int Eo   = in_sizes[1] / 2;     // 800000
    const int Eext = Eo + n;              // 850000

    char* base = (char*)d_ws;
    unsigned short* hAb = (unsigned short*)base;   base += (size_t)n * 256 * 2;
    unsigned short* hBb = (unsigned short*)base;   base += (size_t)n * 256 * 2;
    unsigned short* Xb  = (unsigned short*)base;   base += (size_t)n * 128 * 2;
    unsigned short* Wl1 = (unsigned short*)base;   base += (size_t)128 * 256 * 2;
    unsigned short* Wl2 = (unsigned short*)base;   base += (size_t)256 * 128 * 2;
    unsigned short* Wl3 = (unsigned short*)base;   base += (size_t)128 * 32 * 2;
    float* esrc   = (float*)base;                  base += (size_t)n * 8 * 4;
    float* edst   = (float*)base;                  base += (size_t)n * 8 * 4;
    float* psrc   = (float*)base;                  base += (size_t)n * 4;
    float* pdst   = (float*)base;                  base += (size_t)n * 4;
    int* cnt      = (int*)base;                    base += (size_t)n * 4;
    int* rowptr   = (int*)base;                    base += (size_t)n * 4;
    int* cursors  = (int*)base;                    base += (size_t)n * 4;
    int* csr      = (int*)base;                    base += (size_t)Eext * 4;
    int* csr_src  = (int*)base;                    base += (size_t)Eext * 4;
    int* bsum     = (int*)base;

    const int TB = 256;
    auto nb = [](int tot, int tb) { return (tot + tb - 1) / tb; };

    // ---------------- CSR build (dst-sorted) ----------------
    fill_i<<<nb(n, TB), TB, 0, stream>>>(cnt, 0, n);
    hist_k<<<nb(Eext, TB), TB, 0, stream>>>(ei, cnt, Eo, Eext);
    int nChunks = (n + 1023) / 1024;
    scan1_k<<<nChunks, 256, 0, stream>>>(cnt, rowptr, bsum, n);
    scan2_k<<<1, 64, 0, stream>>>(bsum, nChunks);
    scan3_k<<<nb(n, TB), TB, 0, stream>>>(rowptr, cursors, bsum, n);
    scatter_k<<<nb(Eext, TB), TB, 0, stream>>>(ei, cursors, csr, Eo, Eext);
    sort_k<<<nb(n, TB), TB, 0, stream>>>(rowptr, cnt, csr, ei, csr_src, n, Eo);

    // ---------------- prep: bf16 conversions ----------------
    xprep_k<<<nb(n * 128 / 4, TB), TB, 0, stream>>>(x, Xb, n * 128 / 4);
    wprep_k<<<nb(16 * 256, TB), TB, 0, stream>>>(W1, Wl1, 128, 256);
    wprep_k<<<nb(32 * 128, TB), TB, 0, stream>>>(W2, Wl2, 256, 128);
    wprep_k<<<nb(16 * 32, TB), TB, 0, stream>>>(W3, Wl3, 128, 32);

    // ---------------- Layer 1: K=128, H=8, HC=256 ----------------
    gemm_mfma<128, 256, 8><<<nb(n, 128), 256, 0, stream>>>(Xb, Wl1, as1, ad1, hAb, esrc, edst, n);
    aggr_fused<256, 8, false><<<nb(n * 32, TB), TB, 0, stream>>>(rowptr, cnt, csr_src, esrc, edst, hAb, b1, hBb, nullptr, nullptr, nullptr, n);

    // ---------------- Layer 2: K=256, H=4, HC=128 ----------------
    gemm_mfma<256, 128, 4><<<nb(n, 128), 256, 0, stream>>>(hBb, Wl2, as2, ad2, hAb, esrc, edst, n);
    aggr_fused<128, 4, false><<<nb(n * 16, TB), TB, 0, stream>>>(rowptr, cnt, csr_src, esrc, edst, hAb, b2, hBb, nullptr, nullptr, nullptr, n);

    // ---------------- Layer 3: K=128, H=1, HC=32 (fused rank-1 predictor dots) ----------------
    gemm_mfma<128, 32, 1><<<nb(n, 128), 256, 0, stream>>>(hBb, Wl3, as3, ad3, hAb, esrc, edst, n);
    aggr_fused<32, 1, true><<<nb(n * 4, TB), TB, 0, stream>>>(rowptr, cnt, csr_src, esrc, edst, hAb, b3, nullptr, psrc, pdst, Wp, n);

    // ---------------- predictor ----------------
    predict2_k<<<nb(Eo, TB), TB, 0, stream>>>(ei, psrc, pdst, bp, outp, Eo);
}